// Round 1
// baseline (835.882 us; speedup 1.0000x reference)
//
#include <hip/hip_runtime.h>
#include <math.h>

#define T_    2048
#define DM_   1024
#define NEGF  (-1e30f)
#define BIGF  (1000000.0f)
#define SCALE_ (0.08838834764831845f)   // 1/sqrt(128)

__device__ __forceinline__ float wave_max(float v) {
    #pragma unroll
    for (int off = 32; off >= 1; off >>= 1) v = fmaxf(v, __shfl_xor(v, off, 64));
    return v;
}
__device__ __forceinline__ float wave_sum(float v) {
    #pragma unroll
    for (int off = 32; off >= 1; off >>= 1) v += __shfl_xor(v, off, 64);
    return v;
}

// ---------------- Kernel 1: projections (fp32 tiled GEMM, 64x64 tile) ------
// y = x @ [Wq | Wk | Wv | Wg], cols: [0,1024)=q, [1024,1280)=k, [1280,1536)=v,
// [1536,1560)=gates (sigmoid applied).
__global__ __launch_bounds__(256) void proj_kernel(
    const float* __restrict__ x, const float* __restrict__ Wq,
    const float* __restrict__ Wk, const float* __restrict__ Wv,
    const float* __restrict__ Wg, float* __restrict__ q,
    float* __restrict__ k_raw, float* __restrict__ v, float* __restrict__ gsig)
{
    __shared__ float As[64][17];
    __shared__ float Bs[16][65];
    const int tb = blockIdx.x;            // t tile (32 tiles of 64)
    const int cb = blockIdx.y;            // col tile (25 tiles of 64)
    const int col0 = cb * 64;
    const float* W; int ldw, wcol0, ncol;
    if (col0 < 1024)      { W = Wq; ldw = 1024; wcol0 = col0;        ncol = 1024; }
    else if (col0 < 1280) { W = Wk; ldw = 256;  wcol0 = col0 - 1024; ncol = 256; }
    else if (col0 < 1536) { W = Wv; ldw = 256;  wcol0 = col0 - 1280; ncol = 256; }
    else                  { W = Wg; ldw = 24;   wcol0 = col0 - 1536; ncol = 24; }
    const int tid = threadIdx.x;
    const int tx = tid & 15, ty = tid >> 4;
    const int ac = tid & 15, ar0 = tid >> 4;
    const int bc = tid & 63, br0 = tid >> 6;
    float acc[4][4] = {};
    for (int k0 = 0; k0 < 1024; k0 += 16) {
        #pragma unroll
        for (int i = 0; i < 4; ++i) {
            int r = ar0 + i * 16;
            As[r][ac] = x[(tb * 64 + r) * 1024 + k0 + ac];
        }
        #pragma unroll
        for (int i = 0; i < 4; ++i) {
            int br = br0 + i * 4;
            int wc = wcol0 + bc;
            Bs[br][bc] = (wc < ncol) ? W[(k0 + br) * ldw + wc] : 0.0f;
        }
        __syncthreads();
        #pragma unroll
        for (int kk = 0; kk < 16; ++kk) {
            float a[4], b[4];
            #pragma unroll
            for (int i = 0; i < 4; ++i) a[i] = As[ty * 4 + i][kk];
            #pragma unroll
            for (int jj = 0; jj < 4; ++jj) b[jj] = Bs[kk][tx * 4 + jj];
            #pragma unroll
            for (int i = 0; i < 4; ++i)
                #pragma unroll
                for (int jj = 0; jj < 4; ++jj)
                    acc[i][jj] += a[i] * b[jj];
        }
        __syncthreads();
    }
    #pragma unroll
    for (int i = 0; i < 4; ++i) {
        int tt = tb * 64 + ty * 4 + i;
        #pragma unroll
        for (int jj = 0; jj < 4; ++jj) {
            int cg = col0 + tx * 4 + jj;
            float val = acc[i][jj];
            if (cg < 1024)      q[tt * 1024 + cg] = val;
            else if (cg < 1280) k_raw[tt * 256 + cg - 1024] = val;
            else if (cg < 1536) v[tt * 256 + cg - 1280] = val;
            else if (cg < 1560) gsig[tt * 24 + cg - 1536] = 1.0f / (1.0f + expf(-val));
        }
    }
}

// ---------------- Kernel 2: RoPE on q (in place) and k -> kr ---------------
__global__ __launch_bounds__(64) void rope_kernel(
    float* __restrict__ q, const float* __restrict__ k_raw, float* __restrict__ kr)
{
    const int t = blockIdx.x;
    const int h = blockIdx.y;          // 0..7 q heads, 8..9 kv heads
    const int i = threadIdx.x;         // 0..63 (pair i, i+64)
    float inv = powf(10000.0f, -(float)i / 64.0f);
    float ang = (float)t * inv;
    float sn, cs;
    sincosf(ang, &sn, &cs);
    if (h < 8) {
        float* p = q + t * 1024 + h * 128;
        float x1 = p[i], x2 = p[i + 64];
        p[i]      = x1 * cs - x2 * sn;
        p[i + 64] = x1 * sn + x2 * cs;
    } else {
        const float* s = k_raw + t * 256 + (h - 8) * 128;
        float* d = kr + t * 256 + (h - 8) * 128;
        float x1 = s[i], x2 = s[i + 64];
        d[i]      = x1 * cs - x2 * sn;
        d[i + 64] = x1 * sn + x2 * cs;
    }
}

// ---------------- Kernel 3: pooled k_cmp (roped at j*32) and v_cmp ---------
__global__ __launch_bounds__(256) void pool_kernel(
    const float* __restrict__ k_raw, const float* __restrict__ v_raw,
    const float* __restrict__ wk_pool, const float* __restrict__ wv_pool,
    const float* __restrict__ pe, float* __restrict__ k_cmp, float* __restrict__ v_cmp)
{
    const int j = blockIdx.x;          // block index 0..63
    const int tid = threadIdx.x;
    const int kv = tid >> 7, d = tid & 127;
    float ak = 0.f, av = 0.f;
    for (int s = 0; s < 32; ++s) {
        float pev = pe[(kv * 32 + s) * 128 + d];
        float kk = k_raw[((j * 32 + s) * 2 + kv) * 128 + d] + pev;
        float vv = v_raw[((j * 32 + s) * 2 + kv) * 128 + d] + pev;
        ak += kk * wk_pool[kv * 32 + s];
        av += vv * wv_pool[kv * 32 + s];
    }
    __shared__ float sk[256];
    sk[tid] = ak;
    __syncthreads();
    int i = d & 63;
    float inv = powf(10000.0f, -(float)i / 64.0f);
    float ang = (float)(j * 32) * inv;
    float sn, cs; sincosf(ang, &sn, &cs);
    float x1 = sk[kv * 128 + i], x2 = sk[kv * 128 + i + 64];
    float outv = (d < 64) ? (x1 * cs - x2 * sn) : (x1 * sn + x2 * cs);
    k_cmp[(j * 2 + kv) * 128 + d] = outv;
    v_cmp[(j * 2 + kv) * 128 + d] = av;
}

// ------- Kernel 4: compressed attention + pw + top-8 selection -------------
// one wave per (t, kv); lane = compressed block j
__global__ __launch_bounds__(64) void cmp_sel_kernel(
    const float* __restrict__ q, const float* __restrict__ k_cmp,
    const float* __restrict__ v_cmp, float* __restrict__ o_cmp,
    unsigned long long* __restrict__ sel_mask)
{
    const int t = blockIdx.x;
    const int kv = blockIdx.y;
    const int lane = threadIdx.x;
    __shared__ float qs[4][128];
    __shared__ float ps[64];
    for (int idx = lane; idx < 512; idx += 64)
        qs[idx >> 7][idx & 127] = q[t * 1024 + kv * 512 + idx];
    __syncthreads();
    const int j = lane;
    const float4* krow = (const float4*)&k_cmp[(j * 2 + kv) * 128];
    const bool vis = (t >= j * 32 + 31);
    const bool anyvis = (t >= 31);
    float pw = 0.f;
    for (int g = 0; g < 4; ++g) {
        const float4* qrow = (const float4*)qs[g];
        float s = 0.f;
        #pragma unroll 8
        for (int ii = 0; ii < 32; ++ii) {
            float4 kk = krow[ii], qq = qrow[ii];
            s += kk.x * qq.x + kk.y * qq.y + kk.z * qq.z + kk.w * qq.w;
        }
        s *= SCALE_;
        s = vis ? s : NEGF;
        float m = wave_max(s);
        float e = expf(s - m);
        float sum = wave_sum(e);
        float p = anyvis ? (e / sum) : 0.f;
        pw += p;
        ps[lane] = p;
        __syncthreads();
        float o0 = 0.f, o1 = 0.f;
        for (int jj = 0; jj < 64; ++jj) {
            float pp = ps[jj];
            o0 += pp * v_cmp[(jj * 2 + kv) * 128 + lane];
            o1 += pp * v_cmp[(jj * 2 + kv) * 128 + lane + 64];
        }
        o_cmp[t * 1024 + kv * 512 + g * 128 + lane]      = o0;
        o_cmp[t * 1024 + kv * 512 + g * 128 + lane + 64] = o1;
        __syncthreads();
    }
    // top-8 selection (tie -> lowest index, matching lax.top_k; disallowed
    // picks carry score -1 and are filtered by the > -0.5 test)
    const int cur = t >> 5;
    const int curm1 = cur > 0 ? cur - 1 : 0;
    const bool forced = (j == 0) || (j == cur) || (j == curm1);
    const bool allowed = (j * 32 <= t);
    float sc = allowed ? (pw + (forced ? BIGF : 0.f)) : -1.0f;
    unsigned long long selm = 0ull;
    for (int it = 0; it < 8; ++it) {
        float bv = sc; int bi = j;
        #pragma unroll
        for (int off = 32; off >= 1; off >>= 1) {
            float ov = __shfl_xor(bv, off, 64);
            int   oi = __shfl_xor(bi, off, 64);
            if (ov > bv || (ov == bv && oi < bi)) { bv = ov; bi = oi; }
        }
        if (bv > -0.5f) selm |= (1ull << bi);
        if (j == bi) sc = -3e38f;
    }
    if (lane == 0) sel_mask[t * 2 + kv] = selm;
}

// ------- Kernel 5: selected + sliding-window attention + gated combine -----
// block per (t, kv); wave w handles group head g=w. d_out already holds o_cmp.
__global__ __launch_bounds__(256) void slc_swa_kernel(
    const float* __restrict__ q, const float* __restrict__ kr,
    const float* __restrict__ v, const float* __restrict__ gsig,
    const unsigned long long* __restrict__ sel_mask, float* __restrict__ out)
{
    const int t = blockIdx.x;
    const int kv = blockIdx.y;
    const int tid = threadIdx.x;
    const int w = tid >> 6;      // g
    const int l = tid & 63;
    __shared__ float qs[512];
    __shared__ float sbuf[4][320];
    for (int idx = tid; idx < 512; idx += 256)
        qs[idx] = q[t * 1024 + kv * 512 + idx];
    __syncthreads();
    const float4* qrow = (const float4*)&qs[w * 128];

    // ---- selected branch ----
    unsigned long long mask = sel_mask[t * 2 + kv];
    int blks[8]; int nb = 0;
    { unsigned long long mm = mask;
      while (mm) { blks[nb++] = __ffsll((long long)mm) - 1; mm &= mm - 1; } }
    const int nkeys = nb * 32;
    const int nch = (nb + 1) >> 1;
    for (int ci = 0; ci < nch; ++ci) {
        int kidx = ci * 64 + l;
        int bi = kidx >> 5;
        if (bi < nb) {
            int s = blks[bi] * 32 + (kidx & 31);
            float scv = NEGF;
            if (s <= t) {
                const float4* krow = (const float4*)&kr[(s * 2 + kv) * 128];
                float a = 0.f;
                #pragma unroll 8
                for (int ii = 0; ii < 32; ++ii) {
                    float4 kk = krow[ii], qq = qrow[ii];
                    a += kk.x * qq.x + kk.y * qq.y + kk.z * qq.z + kk.w * qq.w;
                }
                scv = a * SCALE_;
            }
            sbuf[w][kidx] = scv;
        }
    }
    __syncthreads();
    float m = -3e38f;
    for (int kidx = l; kidx < nkeys; kidx += 64) m = fmaxf(m, sbuf[w][kidx]);
    m = wave_max(m);
    float sum = 0.f;
    for (int kidx = l; kidx < nkeys; kidx += 64) {
        float p = expf(sbuf[w][kidx] - m);
        sbuf[w][kidx] = p;
        sum += p;
    }
    sum = wave_sum(sum);
    __syncthreads();
    float rs = 1.0f / sum;
    float os0 = 0.f, os1 = 0.f;
    for (int kidx = 0; kidx < nkeys; ++kidx) {
        int s = blks[kidx >> 5] * 32 + (kidx & 31);
        float p = sbuf[w][kidx];
        const float* vr = &v[(s * 2 + kv) * 128];
        os0 += p * vr[l];
        os1 += p * vr[l + 64];
    }
    os0 *= rs; os1 *= rs;
    __syncthreads();

    // ---- sliding-window branch ----
    const int lo = t > 256 ? t - 256 : 0;
    const int n = t - lo + 1;
    for (int base = 0; base < n; base += 64) {
        int idx = base + l;
        if (idx < n) {
            int s = lo + idx;
            const float4* krow = (const float4*)&kr[(s * 2 + kv) * 128];
            float a = 0.f;
            #pragma unroll 8
            for (int ii = 0; ii < 32; ++ii) {
                float4 kk = krow[ii], qq = qrow[ii];
                a += kk.x * qq.x + kk.y * qq.y + kk.z * qq.z + kk.w * qq.w;
            }
            sbuf[w][idx] = a * SCALE_;
        }
    }
    __syncthreads();
    m = -3e38f;
    for (int idx = l; idx < n; idx += 64) m = fmaxf(m, sbuf[w][idx]);
    m = wave_max(m);
    sum = 0.f;
    for (int idx = l; idx < n; idx += 64) {
        float p = expf(sbuf[w][idx] - m);
        sbuf[w][idx] = p;
        sum += p;
    }
    sum = wave_sum(sum);
    __syncthreads();
    rs = 1.0f / sum;
    float ow0 = 0.f, ow1 = 0.f;
    for (int idx = 0; idx < n; ++idx) {
        float p = sbuf[w][idx];
        const float* vr = &v[((lo + idx) * 2 + kv) * 128];
        ow0 += p * vr[l];
        ow1 += p * vr[l + 64];
    }
    ow0 *= rs; ow1 *= rs;

    // ---- gated combine (out holds o_cmp) ----
    const float gc = gsig[t * 24 + kv * 12 + w * 3 + 0];
    const float gs = gsig[t * 24 + kv * 12 + w * 3 + 1];
    const float gw = gsig[t * 24 + kv * 12 + w * 3 + 2];
    const int oidx = t * 1024 + kv * 512 + w * 128;
    out[oidx + l]      = gc * out[oidx + l]      + gs * os0 + gw * ow0;
    out[oidx + l + 64] = gc * out[oidx + l + 64] + gs * os1 + gw * ow1;
}

extern "C" void kernel_launch(void* const* d_in, const int* in_sizes, int n_in,
                              void* d_out, int out_size, void* d_ws, size_t ws_size,
                              hipStream_t stream)
{
    const float* x       = (const float*)d_in[0];
    const float* Wq      = (const float*)d_in[1];
    const float* Wk      = (const float*)d_in[2];
    const float* Wv      = (const float*)d_in[3];
    const float* Wg      = (const float*)d_in[4];
    const float* wk_pool = (const float*)d_in[5];
    const float* wv_pool = (const float*)d_in[6];
    const float* pe      = (const float*)d_in[7];
    float* out = (float*)d_out;
    float* ws  = (float*)d_ws;

    float* q     = ws;                    // 2,097,152 floats
    float* k_raw = q + 2097152;           //   524,288
    float* kr    = k_raw + 524288;        //   524,288
    float* v     = kr + 524288;           //   524,288
    float* gsig  = v + 524288;            //    49,152
    float* k_cmp = gsig + 49152;          //    16,384
    float* v_cmp = k_cmp + 16384;         //    16,384
    unsigned long long* sel = (unsigned long long*)(v_cmp + 16384); // 4096 u64
    // total ~15 MB of d_ws

    hipLaunchKernelGGL(proj_kernel, dim3(32, 25), dim3(256), 0, stream,
                       x, Wq, Wk, Wv, Wg, q, k_raw, v, gsig);
    hipLaunchKernelGGL(rope_kernel, dim3(2048, 10), dim3(64), 0, stream,
                       q, k_raw, kr);
    hipLaunchKernelGGL(pool_kernel, dim3(64), dim3(256), 0, stream,
                       k_raw, v, wk_pool, wv_pool, pe, k_cmp, v_cmp);
    hipLaunchKernelGGL(cmp_sel_kernel, dim3(2048, 2), dim3(64), 0, stream,
                       q, k_cmp, v_cmp, out, sel);
    hipLaunchKernelGGL(slc_swa_kernel, dim3(2048, 2), dim3(256), 0, stream,
                       q, kr, v, gsig, sel, out);
}

// Round 2
// 420.204 us; speedup vs baseline: 1.9892x; 1.9892x over previous
//
#include <hip/hip_runtime.h>
#include <math.h>

#define NEGF  (-1e30f)
#define BIGF  (1000000.0f)
#define SCALE_ (0.08838834764831845f)   // 1/sqrt(128)

typedef __attribute__((ext_vector_type(4))) float f32x4;
typedef __attribute__((ext_vector_type(8))) short short8;

__device__ __forceinline__ float wave_max(float v) {
    #pragma unroll
    for (int off = 32; off >= 1; off >>= 1) v = fmaxf(v, __shfl_xor(v, off, 64));
    return v;
}
__device__ __forceinline__ float wave_sum(float v) {
    #pragma unroll
    for (int off = 32; off >= 1; off >>= 1) v += __shfl_xor(v, off, 64);
    return v;
}
__device__ __forceinline__ float grp16_max(float v) {
    #pragma unroll
    for (int off = 8; off >= 1; off >>= 1) v = fmaxf(v, __shfl_xor(v, off, 64));
    return v;
}
__device__ __forceinline__ float grp16_sum(float v) {
    #pragma unroll
    for (int off = 8; off >= 1; off >>= 1) v += __shfl_xor(v, off, 64);
    return v;
}
__device__ __forceinline__ short bf16_of(float f) {
    union { float f; unsigned u; } x; x.f = f;
    unsigned r = x.u + 0x7fffu + ((x.u >> 16) & 1u);
    return (short)(r >> 16);
}

// ---------------- Kernel 1: projections (fp32 tiled GEMM, 64x64 tile) ------
__global__ __launch_bounds__(256) void proj_kernel(
    const float* __restrict__ x, const float* __restrict__ Wq,
    const float* __restrict__ Wk, const float* __restrict__ Wv,
    const float* __restrict__ Wg, float* __restrict__ q,
    float* __restrict__ k_raw, float* __restrict__ v, float* __restrict__ gsig)
{
    __shared__ float As[64][17];
    __shared__ float Bs[16][65];
    const int tb = blockIdx.x;
    const int cb = blockIdx.y;
    const int col0 = cb * 64;
    const float* W; int ldw, wcol0, ncol;
    if (col0 < 1024)      { W = Wq; ldw = 1024; wcol0 = col0;        ncol = 1024; }
    else if (col0 < 1280) { W = Wk; ldw = 256;  wcol0 = col0 - 1024; ncol = 256; }
    else if (col0 < 1536) { W = Wv; ldw = 256;  wcol0 = col0 - 1280; ncol = 256; }
    else                  { W = Wg; ldw = 24;   wcol0 = col0 - 1536; ncol = 24; }
    const int tid = threadIdx.x;
    const int tx = tid & 15, ty = tid >> 4;
    const int ac = tid & 15, ar0 = tid >> 4;
    const int bc = tid & 63, br0 = tid >> 6;
    float acc[4][4] = {};
    for (int k0 = 0; k0 < 1024; k0 += 16) {
        #pragma unroll
        for (int i = 0; i < 4; ++i) {
            int r = ar0 + i * 16;
            As[r][ac] = x[(tb * 64 + r) * 1024 + k0 + ac];
        }
        #pragma unroll
        for (int i = 0; i < 4; ++i) {
            int br = br0 + i * 4;
            int wc = wcol0 + bc;
            Bs[br][bc] = (wc < ncol) ? W[(k0 + br) * ldw + wc] : 0.0f;
        }
        __syncthreads();
        #pragma unroll
        for (int kk = 0; kk < 16; ++kk) {
            float a[4], b[4];
            #pragma unroll
            for (int i = 0; i < 4; ++i) a[i] = As[ty * 4 + i][kk];
            #pragma unroll
            for (int jj = 0; jj < 4; ++jj) b[jj] = Bs[kk][tx * 4 + jj];
            #pragma unroll
            for (int i = 0; i < 4; ++i)
                #pragma unroll
                for (int jj = 0; jj < 4; ++jj)
                    acc[i][jj] += a[i] * b[jj];
        }
        __syncthreads();
    }
    #pragma unroll
    for (int i = 0; i < 4; ++i) {
        int tt = tb * 64 + ty * 4 + i;
        #pragma unroll
        for (int jj = 0; jj < 4; ++jj) {
            int cg = col0 + tx * 4 + jj;
            float val = acc[i][jj];
            if (cg < 1024)      q[tt * 1024 + cg] = val;
            else if (cg < 1280) k_raw[tt * 256 + cg - 1024] = val;
            else if (cg < 1536) v[tt * 256 + cg - 1280] = val;
            else if (cg < 1560) gsig[tt * 24 + cg - 1536] = 1.0f / (1.0f + expf(-val));
        }
    }
}

// ------ Kernel 2: RoPE on q (in place) and k -> kr, plus bf16 copies -------
__global__ __launch_bounds__(64) void rope_conv_kernel(
    float* __restrict__ q, const float* __restrict__ k_raw, float* __restrict__ kr,
    short* __restrict__ qb, short* __restrict__ krb)
{
    const int t = blockIdx.x;
    const int h = blockIdx.y;          // 0..7 q heads, 8..9 kv heads
    const int i = threadIdx.x;         // 0..63
    float inv = powf(10000.0f, -(float)i / 64.0f);
    float ang = (float)t * inv;
    float sn, cs;
    sincosf(ang, &sn, &cs);
    if (h < 8) {
        float* p = q + t * 1024 + h * 128;
        float x1 = p[i], x2 = p[i + 64];
        float r1 = x1 * cs - x2 * sn;
        float r2 = x1 * sn + x2 * cs;
        p[i] = r1; p[i + 64] = r2;
        qb[t * 1024 + h * 128 + i]      = bf16_of(r1);
        qb[t * 1024 + h * 128 + i + 64] = bf16_of(r2);
    } else {
        const float* s = k_raw + t * 256 + (h - 8) * 128;
        float* d = kr + t * 256 + (h - 8) * 128;
        float x1 = s[i], x2 = s[i + 64];
        float r1 = x1 * cs - x2 * sn;
        float r2 = x1 * sn + x2 * cs;
        d[i] = r1; d[i + 64] = r2;
        krb[t * 256 + (h - 8) * 128 + i]      = bf16_of(r1);
        krb[t * 256 + (h - 8) * 128 + i + 64] = bf16_of(r2);
    }
}

// ------ Kernel 2b: v (fp32 [s][kv][d]) -> vT bf16 [kv][d][s] ---------------
__global__ __launch_bounds__(256) void vtrans_kernel(
    const float* __restrict__ v, short* __restrict__ vT)
{
    __shared__ short tile[32][33];
    const int s0 = blockIdx.x * 32, d0 = blockIdx.y * 32, kv = blockIdx.z;
    const int c = threadIdx.x & 31, r0 = threadIdx.x >> 5;  // 8 rows per pass
    #pragma unroll
    for (int rr = 0; rr < 32; rr += 8) {
        int r = r0 + rr;
        tile[r][c] = bf16_of(v[((size_t)(s0 + r) * 2 + kv) * 128 + d0 + c]);
    }
    __syncthreads();
    #pragma unroll
    for (int rr = 0; rr < 32; rr += 8) {
        int r = r0 + rr;
        vT[((size_t)kv * 128 + d0 + r) * 2048 + s0 + c] = tile[c][r];
    }
}

// ------- Kernel 3: pooled k_cmp (roped at j*32) and v_cmp ------------------
__global__ __launch_bounds__(256) void pool_kernel(
    const float* __restrict__ k_raw, const float* __restrict__ v_raw,
    const float* __restrict__ wk_pool, const float* __restrict__ wv_pool,
    const float* __restrict__ pe, float* __restrict__ k_cmp, float* __restrict__ v_cmp)
{
    const int j = blockIdx.x;
    const int tid = threadIdx.x;
    const int kv = tid >> 7, d = tid & 127;
    float ak = 0.f, av = 0.f;
    for (int s = 0; s < 32; ++s) {
        float pev = pe[(kv * 32 + s) * 128 + d];
        float kk = k_raw[((j * 32 + s) * 2 + kv) * 128 + d] + pev;
        float vv = v_raw[((j * 32 + s) * 2 + kv) * 128 + d] + pev;
        ak += kk * wk_pool[kv * 32 + s];
        av += vv * wv_pool[kv * 32 + s];
    }
    __shared__ float sk[256];
    sk[tid] = ak;
    __syncthreads();
    int i = d & 63;
    float inv = powf(10000.0f, -(float)i / 64.0f);
    float ang = (float)(j * 32) * inv;
    float sn, cs; sincosf(ang, &sn, &cs);
    float x1 = sk[kv * 128 + i], x2 = sk[kv * 128 + i + 64];
    float outv = (d < 64) ? (x1 * cs - x2 * sn) : (x1 * sn + x2 * cs);
    k_cmp[(j * 2 + kv) * 128 + d] = outv;
    v_cmp[(j * 2 + kv) * 128 + d] = av;
}

// ------- Kernel 4: compressed attention + pw + top-8 selection (fp32) ------
__global__ __launch_bounds__(64) void cmp_sel_kernel(
    const float* __restrict__ q, const float* __restrict__ k_cmp,
    const float* __restrict__ v_cmp, float* __restrict__ o_cmp,
    unsigned long long* __restrict__ sel_mask)
{
    const int t = blockIdx.x;
    const int kv = blockIdx.y;
    const int lane = threadIdx.x;
    __shared__ float qs[4][128];
    __shared__ float ps[64];
    for (int idx = lane; idx < 512; idx += 64)
        qs[idx >> 7][idx & 127] = q[t * 1024 + kv * 512 + idx];
    __syncthreads();
    const int j = lane;
    const float4* krow = (const float4*)&k_cmp[(j * 2 + kv) * 128];
    const bool vis = (t >= j * 32 + 31);
    const bool anyvis = (t >= 31);
    float pw = 0.f;
    for (int g = 0; g < 4; ++g) {
        const float4* qrow = (const float4*)qs[g];
        float s = 0.f;
        #pragma unroll 8
        for (int ii = 0; ii < 32; ++ii) {
            float4 kk = krow[ii], qq = qrow[ii];
            s += kk.x * qq.x + kk.y * qq.y + kk.z * qq.z + kk.w * qq.w;
        }
        s *= SCALE_;
        s = vis ? s : NEGF;
        float m = wave_max(s);
        float e = expf(s - m);
        float sum = wave_sum(e);
        float p = anyvis ? (e / sum) : 0.f;
        pw += p;
        ps[lane] = p;
        __syncthreads();
        float o0 = 0.f, o1 = 0.f;
        for (int jj = 0; jj < 64; ++jj) {
            float pp = ps[jj];
            o0 += pp * v_cmp[(jj * 2 + kv) * 128 + lane];
            o1 += pp * v_cmp[(jj * 2 + kv) * 128 + lane + 64];
        }
        o_cmp[t * 1024 + kv * 512 + g * 128 + lane]      = o0;
        o_cmp[t * 1024 + kv * 512 + g * 128 + lane + 64] = o1;
        __syncthreads();
    }
    const int cur = t >> 5;
    const int curm1 = cur > 0 ? cur - 1 : 0;
    const bool forced = (j == 0) || (j == cur) || (j == curm1);
    const bool allowed = (j * 32 <= t);
    float sc = allowed ? (pw + (forced ? BIGF : 0.f)) : -1.0f;
    unsigned long long selm = 0ull;
    for (int it = 0; it < 8; ++it) {
        float bv = sc; int bi = j;
        #pragma unroll
        for (int off = 32; off >= 1; off >>= 1) {
            float ov = __shfl_xor(bv, off, 64);
            int   oi = __shfl_xor(bi, off, 64);
            if (ov > bv || (ov == bv && oi < bi)) { bv = ov; bi = oi; }
        }
        if (bv > -0.5f) selm |= (1ull << bi);
        if (j == bi) sc = -3e38f;
    }
    if (lane == 0) sel_mask[t * 2 + kv] = selm;
}

// ------- Kernel 5: sliding-window attention, bf16 MFMA flash ---------------
// block = (32-query tile, kv); wave = g. Writes o_swa into d_out.
__global__ __launch_bounds__(256) void swa_kernel(
    const short* __restrict__ qb, const short* __restrict__ krb,
    const short* __restrict__ vT, float* __restrict__ out)
{
    const int t0 = blockIdx.x * 32;
    const int kv = blockIdx.y;
    const int w  = threadIdx.x >> 6;
    const int l  = threadIdx.x & 63;
    const int l16 = l & 15, g4 = l >> 4;
    __shared__ __align__(16) short plds[4][32][40];

    short8 qf[2][4];
    #pragma unroll
    for (int mt = 0; mt < 2; ++mt)
        #pragma unroll
        for (int ks = 0; ks < 4; ++ks)
            qf[mt][ks] = *(const short8*)(qb + ((size_t)(t0 + mt * 16 + l16) * 8 + kv * 4 + w) * 128 + ks * 32 + g4 * 8);

    f32x4 acc[2][8];
    #pragma unroll
    for (int mt = 0; mt < 2; ++mt)
        #pragma unroll
        for (int nt = 0; nt < 8; ++nt) acc[mt][nt] = (f32x4)0.f;
    float m_r[2][4], l_r[2][4];
    #pragma unroll
    for (int mt = 0; mt < 2; ++mt)
        #pragma unroll
        for (int r = 0; r < 4; ++r) { m_r[mt][r] = NEGF; l_r[mt][r] = 0.f; }

    const int sLo = (t0 >= 256) ? (t0 - 256) : 0;
    for (int s0 = sLo; s0 <= t0 + 31; s0 += 32) {
        f32x4 sc[2][2];
        #pragma unroll
        for (int mt = 0; mt < 2; ++mt)
            #pragma unroll
            for (int nt = 0; nt < 2; ++nt) sc[mt][nt] = (f32x4)0.f;
        #pragma unroll
        for (int nt = 0; nt < 2; ++nt) {
            short8 kf[4];
            #pragma unroll
            for (int ks = 0; ks < 4; ++ks)
                kf[ks] = *(const short8*)(krb + ((size_t)(s0 + nt * 16 + l16) * 2 + kv) * 128 + ks * 32 + g4 * 8);
            #pragma unroll
            for (int mt = 0; mt < 2; ++mt)
                #pragma unroll
                for (int ks = 0; ks < 4; ++ks)
                    sc[mt][nt] = __builtin_amdgcn_mfma_f32_16x16x32_bf16(qf[mt][ks], kf[ks], sc[mt][nt], 0, 0, 0);
        }
        // online softmax update (queries: row = mt*16 + 4*g4 + r; keys: s0 + nt*16 + l16)
        #pragma unroll
        for (int mt = 0; mt < 2; ++mt) {
            #pragma unroll
            for (int r = 0; r < 4; ++r) {
                const int tq = t0 + mt * 16 + g4 * 4 + r;
                const int sk0 = s0 + l16, sk1 = s0 + 16 + l16;
                const bool v0 = (sk0 <= tq) && (sk0 >= tq - 256);
                const bool v1 = (sk1 <= tq) && (sk1 >= tq - 256);
                float s0v = v0 ? sc[mt][0][r] * SCALE_ : NEGF;
                float s1v = v1 ? sc[mt][1][r] * SCALE_ : NEGF;
                float mx = grp16_max(fmaxf(s0v, s1v));
                float mnew = fmaxf(m_r[mt][r], mx);
                float al = __expf(m_r[mt][r] - mnew);
                float p0 = v0 ? __expf(s0v - mnew) : 0.f;
                float p1 = v1 ? __expf(s1v - mnew) : 0.f;
                float rs = grp16_sum(p0 + p1);
                l_r[mt][r] = l_r[mt][r] * al + rs;
                m_r[mt][r] = mnew;
                #pragma unroll
                for (int nt = 0; nt < 8; ++nt) acc[mt][nt][r] *= al;
                plds[w][mt * 16 + g4 * 4 + r][l16]      = bf16_of(p0);
                plds[w][mt * 16 + g4 * 4 + r][16 + l16] = bf16_of(p1);
            }
        }
        short8 pa[2];
        #pragma unroll
        for (int mt = 0; mt < 2; ++mt)
            pa[mt] = *(const short8*)(&plds[w][mt * 16 + l16][g4 * 8]);
        #pragma unroll
        for (int nt = 0; nt < 8; ++nt) {
            short8 vf = *(const short8*)(vT + ((size_t)kv * 128 + nt * 16 + l16) * 2048 + s0 + g4 * 8);
            #pragma unroll
            for (int mt = 0; mt < 2; ++mt)
                acc[mt][nt] = __builtin_amdgcn_mfma_f32_16x16x32_bf16(pa[mt], vf, acc[mt][nt], 0, 0, 0);
        }
    }
    #pragma unroll
    for (int mt = 0; mt < 2; ++mt)
        #pragma unroll
        for (int r = 0; r < 4; ++r) {
            const int tq = t0 + mt * 16 + g4 * 4 + r;
            const float rl = 1.0f / l_r[mt][r];
            #pragma unroll
            for (int nt = 0; nt < 8; ++nt)
                out[(size_t)tq * 1024 + (kv * 4 + w) * 128 + nt * 16 + l16] = acc[mt][nt][r] * rl;
        }
}

// ------- Kernel 6: selected attention (union of 16 queries) + combine ------
// block = (16-query tile, kv); wave = g. Reads o_cmp (ws) and o_swa (d_out),
// writes gated combine into d_out.
__global__ __launch_bounds__(256) void slc_kernel(
    const short* __restrict__ qb, const short* __restrict__ krb,
    const short* __restrict__ vT, const unsigned long long* __restrict__ sel,
    const float* __restrict__ gsig, const float* __restrict__ o_cmp,
    float* __restrict__ out)
{
    const int t0 = blockIdx.x * 16;
    const int kv = blockIdx.y;
    const int w  = threadIdx.x >> 6;
    const int l  = threadIdx.x & 63;
    const int l16 = l & 15, g4 = l >> 4;
    __shared__ __align__(16) short plds[4][16][40];
    __shared__ unsigned long long qm[16];
    __shared__ unsigned char blist[64];
    __shared__ int nbs;
    if (threadIdx.x < 16) qm[threadIdx.x] = sel[(size_t)(t0 + threadIdx.x) * 2 + kv];
    __syncthreads();
    if (threadIdx.x == 0) {
        unsigned long long u = 0ull;
        #pragma unroll
        for (int i = 0; i < 16; ++i) u |= qm[i];
        int n = 0;
        while (u) { blist[n++] = (unsigned char)(__ffsll((long long)u) - 1); u &= u - 1; }
        nbs = n;
    }
    __syncthreads();

    short8 qf[4];
    #pragma unroll
    for (int ks = 0; ks < 4; ++ks)
        qf[ks] = *(const short8*)(qb + ((size_t)(t0 + l16) * 8 + kv * 4 + w) * 128 + ks * 32 + g4 * 8);

    f32x4 acc[8];
    #pragma unroll
    for (int nt = 0; nt < 8; ++nt) acc[nt] = (f32x4)0.f;
    float m_r[4], l_r[4];
    #pragma unroll
    for (int r = 0; r < 4; ++r) { m_r[r] = NEGF; l_r[r] = 0.f; }

    const int nb = nbs;
    for (int bi = 0; bi < nb; ++bi) {
        const int j = blist[bi];
        const int s0 = j * 32;
        f32x4 sc[2];
        sc[0] = (f32x4)0.f; sc[1] = (f32x4)0.f;
        #pragma unroll
        for (int nt = 0; nt < 2; ++nt) {
            short8 kf[4];
            #pragma unroll
            for (int ks = 0; ks < 4; ++ks)
                kf[ks] = *(const short8*)(krb + ((size_t)(s0 + nt * 16 + l16) * 2 + kv) * 128 + ks * 32 + g4 * 8);
            #pragma unroll
            for (int ks = 0; ks < 4; ++ks)
                sc[nt] = __builtin_amdgcn_mfma_f32_16x16x32_bf16(qf[ks], kf[ks], sc[nt], 0, 0, 0);
        }
        #pragma unroll
        for (int r = 0; r < 4; ++r) {
            const int ql = g4 * 4 + r;
            const int tq = t0 + ql;
            const bool inmask = (qm[ql] >> j) & 1ull;
            const int sk0 = s0 + l16, sk1 = s0 + 16 + l16;
            const bool v0 = inmask && (sk0 <= tq);
            const bool v1 = inmask && (sk1 <= tq);
            float s0v = v0 ? sc[0][r] * SCALE_ : NEGF;
            float s1v = v1 ? sc[1][r] * SCALE_ : NEGF;
            float mx = grp16_max(fmaxf(s0v, s1v));
            float mnew = fmaxf(m_r[r], mx);
            float al = __expf(m_r[r] - mnew);
            float p0 = v0 ? __expf(s0v - mnew) : 0.f;
            float p1 = v1 ? __expf(s1v - mnew) : 0.f;
            float rs = grp16_sum(p0 + p1);
            l_r[r] = l_r[r] * al + rs;
            m_r[r] = mnew;
            #pragma unroll
            for (int nt = 0; nt < 8; ++nt) acc[nt][r] *= al;
            plds[w][ql][l16]      = bf16_of(p0);
            plds[w][ql][16 + l16] = bf16_of(p1);
        }
        short8 pa = *(const short8*)(&plds[w][l16][g4 * 8]);
        #pragma unroll
        for (int nt = 0; nt < 8; ++nt) {
            short8 vf = *(const short8*)(vT + ((size_t)kv * 128 + nt * 16 + l16) * 2048 + s0 + g4 * 8);
            acc[nt] = __builtin_amdgcn_mfma_f32_16x16x32_bf16(pa, vf, acc[nt], 0, 0, 0);
        }
    }
    // epilogue: gated combine
    #pragma unroll
    for (int r = 0; r < 4; ++r) {
        const int tq = t0 + g4 * 4 + r;
        const float rl = 1.0f / l_r[r];
        const float gc = gsig[tq * 24 + kv * 12 + w * 3 + 0];
        const float gs = gsig[tq * 24 + kv * 12 + w * 3 + 1];
        const float gw = gsig[tq * 24 + kv * 12 + w * 3 + 2];
        #pragma unroll
        for (int nt = 0; nt < 8; ++nt) {
            const size_t idx = (size_t)tq * 1024 + (kv * 4 + w) * 128 + nt * 16 + l16;
            out[idx] = gc * o_cmp[idx] + gs * (acc[nt][r] * rl) + gw * out[idx];
        }
    }
}

extern "C" void kernel_launch(void* const* d_in, const int* in_sizes, int n_in,
                              void* d_out, int out_size, void* d_ws, size_t ws_size,
                              hipStream_t stream)
{
    const float* x       = (const float*)d_in[0];
    const float* Wq      = (const float*)d_in[1];
    const float* Wk      = (const float*)d_in[2];
    const float* Wv      = (const float*)d_in[3];
    const float* Wg      = (const float*)d_in[4];
    const float* wk_pool = (const float*)d_in[5];
    const float* wv_pool = (const float*)d_in[6];
    const float* pe      = (const float*)d_in[7];
    float* out = (float*)d_out;
    float* ws  = (float*)d_ws;

    float* q     = ws;                      // 2,097,152
    float* k_raw = q + 2097152;             //   524,288
    float* kr    = k_raw + 524288;          //   524,288
    float* v     = kr + 524288;             //   524,288
    float* gsig  = v + 524288;              //    49,152
    float* k_cmp = gsig + 49152;            //    16,384
    float* v_cmp = k_cmp + 16384;           //    16,384
    unsigned long long* sel = (unsigned long long*)(v_cmp + 16384); // 8,192 floats
    float* o_cmp = v_cmp + 16384 + 8192;    // 2,097,152
    short* qb    = (short*)(o_cmp + 2097152);   // 1,048,576 floats
    short* krb   = (short*)(o_cmp + 2097152 + 1048576); // 262,144 floats
    short* vT    = (short*)(o_cmp + 2097152 + 1048576 + 262144); // 262,144 floats

    hipLaunchKernelGGL(proj_kernel, dim3(32, 25), dim3(256), 0, stream,
                       x, Wq, Wk, Wv, Wg, q, k_raw, v, gsig);
    hipLaunchKernelGGL(rope_conv_kernel, dim3(2048, 10), dim3(64), 0, stream,
                       q, k_raw, kr, qb, krb);
    hipLaunchKernelGGL(vtrans_kernel, dim3(64, 4, 2), dim3(256), 0, stream,
                       v, vT);
    hipLaunchKernelGGL(pool_kernel, dim3(64), dim3(256), 0, stream,
                       k_raw, v, wk_pool, wv_pool, pe, k_cmp, v_cmp);
    hipLaunchKernelGGL(cmp_sel_kernel, dim3(2048, 2), dim3(64), 0, stream,
                       q, k_cmp, v_cmp, o_cmp, sel);
    hipLaunchKernelGGL(swa_kernel, dim3(64, 2), dim3(256), 0, stream,
                       qb, krb, vT, out);
    hipLaunchKernelGGL(slc_kernel, dim3(128, 2), dim3(256), 0, stream,
                       qb, krb, vT, sel, gsig, o_cmp, out);
}

// Round 3
// 359.543 us; speedup vs baseline: 2.3248x; 1.1687x over previous
//
#include <hip/hip_runtime.h>
#include <math.h>

#define NEGF  (-1e30f)
#define BIGF  (1000000.0f)
#define SCALE_ (0.08838834764831845f)   // 1/sqrt(128)
#define L2INV_ (0.20762050593046014f)   // log2(10000)/64

typedef __attribute__((ext_vector_type(4))) float f32x4;
typedef __attribute__((ext_vector_type(8))) short short8;
typedef __attribute__((ext_vector_type(4))) short short4v;
typedef __attribute__((ext_vector_type(8))) _Float16 half8;

__device__ __forceinline__ float wave_max(float v) {
    #pragma unroll
    for (int off = 32; off >= 1; off >>= 1) v = fmaxf(v, __shfl_xor(v, off, 64));
    return v;
}
__device__ __forceinline__ float wave_sum(float v) {
    #pragma unroll
    for (int off = 32; off >= 1; off >>= 1) v += __shfl_xor(v, off, 64);
    return v;
}
__device__ __forceinline__ float grp16_max(float v) {
    #pragma unroll
    for (int off = 8; off >= 1; off >>= 1) v = fmaxf(v, __shfl_xor(v, off, 64));
    return v;
}
__device__ __forceinline__ float grp16_sum(float v) {
    #pragma unroll
    for (int off = 8; off >= 1; off >>= 1) v += __shfl_xor(v, off, 64);
    return v;
}
__device__ __forceinline__ short bf16_of(float f) {
    union { float f; unsigned u; } x; x.f = f;
    unsigned r = x.u + 0x7fffu + ((x.u >> 16) & 1u);
    return (short)(r >> 16);
}
__device__ __forceinline__ short f16_of(float f) {
    _Float16 h = (_Float16)f;
    union { _Float16 h; short s; } u; u.h = h;
    return u.s;
}
__device__ __forceinline__ float f32_of_f16(short s) {
    union { _Float16 h; short s; } u; u.s = s;
    return (float)u.h;
}

// -------- Kernel 0a: x (fp32) -> xhi/xlo fp16 split ------------------------
__global__ __launch_bounds__(256) void xconv_kernel(
    const float* __restrict__ x, short* __restrict__ xhi, short* __restrict__ xlo)
{
    const int i = blockIdx.x * 1024 + threadIdx.x * 4;
    float4 f = *(const float4*)(x + i);
    short4v hi, lo;
    float fv[4] = {f.x, f.y, f.z, f.w};
    #pragma unroll
    for (int c = 0; c < 4; ++c) {
        short h = f16_of(fv[c]);
        hi[c] = h;
        lo[c] = f16_of(fv[c] - f32_of_f16(h));
    }
    *(short4v*)(xhi + i) = hi;
    *(short4v*)(xlo + i) = lo;
}

// -------- Kernel 0b: W's -> WT fp16 split, transposed [1600][1024] ---------
__global__ __launch_bounds__(256) void wconv_kernel(
    const float* __restrict__ Wq, const float* __restrict__ Wk,
    const float* __restrict__ Wv, const float* __restrict__ Wg,
    short* __restrict__ wthi, short* __restrict__ wtlo)
{
    __shared__ float tile[32][33];
    const int ct = blockIdx.x, kt = blockIdx.y;
    const int c = threadIdx.x & 31, r0 = threadIdx.x >> 5;
    #pragma unroll
    for (int rr = 0; rr < 32; rr += 8) {
        int k = kt * 32 + r0 + rr;
        int gc = ct * 32 + c;
        float val;
        if (gc < 1024)      val = Wq[k * 1024 + gc];
        else if (gc < 1280) val = Wk[k * 256 + gc - 1024];
        else if (gc < 1536) val = Wv[k * 256 + gc - 1280];
        else if (gc < 1560) val = Wg[k * 24 + gc - 1536];
        else                val = 0.f;
        tile[r0 + rr][c] = val;
    }
    __syncthreads();
    #pragma unroll
    for (int rr = 0; rr < 32; rr += 8) {
        int col = ct * 32 + r0 + rr;
        int k = kt * 32 + c;
        float val = tile[c][r0 + rr];
        short hi = f16_of(val);
        short lo = f16_of(val - f32_of_f16(hi));
        wthi[(size_t)col * 1024 + k] = hi;
        wtlo[(size_t)col * 1024 + k] = lo;
    }
}

// -------- Kernel 1: projections via split-fp16 MFMA (fp32-class accuracy) --
// y = x @ [Wq|Wk|Wv|Wg]; BM=128 x BN=64 tile, 8 waves of 32x32.
__global__ __launch_bounds__(512) void proj_mfma_kernel(
    const short* __restrict__ xhi, const short* __restrict__ xlo,
    const short* __restrict__ wthi, const short* __restrict__ wtlo,
    float* __restrict__ q, float* __restrict__ k_raw,
    float* __restrict__ v, float* __restrict__ gsig)
{
    const int cb = blockIdx.x;             // 25 col tiles of 64
    const int tb = blockIdx.y;             // 16 row tiles of 128
    const int w = threadIdx.x >> 6;
    const int l = threadIdx.x & 63;
    const int l16 = l & 15, g4 = l >> 4;
    const int wrow = tb * 128 + (w >> 1) * 32;
    const int wcol = cb * 64 + (w & 1) * 32;
    f32x4 acc[2][2];
    #pragma unroll
    for (int mt = 0; mt < 2; ++mt)
        #pragma unroll
        for (int nt = 0; nt < 2; ++nt) acc[mt][nt] = (f32x4)0.f;

    for (int k0 = 0; k0 < 1024; k0 += 32) {
        half8 ah[2], al[2], bh[2], bl[2];
        #pragma unroll
        for (int mt = 0; mt < 2; ++mt) {
            const size_t aoff = (size_t)(wrow + mt * 16 + l16) * 1024 + k0 + g4 * 8;
            ah[mt] = *(const half8*)(const void*)(xhi + aoff);
            al[mt] = *(const half8*)(const void*)(xlo + aoff);
        }
        #pragma unroll
        for (int nt = 0; nt < 2; ++nt) {
            const size_t boff = (size_t)(wcol + nt * 16 + l16) * 1024 + k0 + g4 * 8;
            bh[nt] = *(const half8*)(const void*)(wthi + boff);
            bl[nt] = *(const half8*)(const void*)(wtlo + boff);
        }
        #pragma unroll
        for (int mt = 0; mt < 2; ++mt)
            #pragma unroll
            for (int nt = 0; nt < 2; ++nt) {
                acc[mt][nt] = __builtin_amdgcn_mfma_f32_16x16x32_f16(ah[mt], bh[nt], acc[mt][nt], 0, 0, 0);
                acc[mt][nt] = __builtin_amdgcn_mfma_f32_16x16x32_f16(ah[mt], bl[nt], acc[mt][nt], 0, 0, 0);
                acc[mt][nt] = __builtin_amdgcn_mfma_f32_16x16x32_f16(al[mt], bh[nt], acc[mt][nt], 0, 0, 0);
            }
    }
    #pragma unroll
    for (int mt = 0; mt < 2; ++mt) {
        #pragma unroll
        for (int r = 0; r < 4; ++r) {
            const int tt = wrow + mt * 16 + g4 * 4 + r;
            #pragma unroll
            for (int nt = 0; nt < 2; ++nt) {
                const int cg = wcol + nt * 16 + l16;
                const float val = acc[mt][nt][r];
                if (cg < 1024)      q[(size_t)tt * 1024 + cg] = val;
                else if (cg < 1280) k_raw[(size_t)tt * 256 + cg - 1024] = val;
                else if (cg < 1536) v[(size_t)tt * 256 + cg - 1280] = val;
                else if (cg < 1560) gsig[(size_t)tt * 24 + cg - 1536] = 1.0f / (1.0f + expf(-val));
            }
        }
    }
}

// ------ Kernel 2: RoPE on q (in place) and k, plus bf16 copies -------------
__global__ __launch_bounds__(64) void rope_conv_kernel(
    float* __restrict__ q, const float* __restrict__ k_raw,
    short* __restrict__ qb, short* __restrict__ krb)
{
    const int t = blockIdx.x;
    const int h = blockIdx.y;          // 0..7 q heads, 8..9 kv heads
    const int i = threadIdx.x;         // 0..63
    float inv = exp2f(-(float)i * L2INV_);
    float ang = (float)t * inv;
    float sn, cs;
    sincosf(ang, &sn, &cs);
    if (h < 8) {
        float* p = q + t * 1024 + h * 128;
        float x1 = p[i], x2 = p[i + 64];
        float r1 = x1 * cs - x2 * sn;
        float r2 = x1 * sn + x2 * cs;
        p[i] = r1; p[i + 64] = r2;
        qb[t * 1024 + h * 128 + i]      = bf16_of(r1);
        qb[t * 1024 + h * 128 + i + 64] = bf16_of(r2);
    } else {
        const float* s = k_raw + t * 256 + (h - 8) * 128;
        float x1 = s[i], x2 = s[i + 64];
        krb[t * 256 + (h - 8) * 128 + i]      = bf16_of(x1 * cs - x2 * sn);
        krb[t * 256 + (h - 8) * 128 + i + 64] = bf16_of(x1 * sn + x2 * cs);
    }
}

// ------ Kernel 2b: v (fp32 [s][kv][d]) -> vT bf16 [kv][d][s] ---------------
__global__ __launch_bounds__(256) void vtrans_kernel(
    const float* __restrict__ v, short* __restrict__ vT)
{
    __shared__ short tile[32][33];
    const int s0 = blockIdx.x * 32, d0 = blockIdx.y * 32, kv = blockIdx.z;
    const int c = threadIdx.x & 31, r0 = threadIdx.x >> 5;
    #pragma unroll
    for (int rr = 0; rr < 32; rr += 8) {
        int r = r0 + rr;
        tile[r][c] = bf16_of(v[((size_t)(s0 + r) * 2 + kv) * 128 + d0 + c]);
    }
    __syncthreads();
    #pragma unroll
    for (int rr = 0; rr < 32; rr += 8) {
        int r = r0 + rr;
        vT[((size_t)kv * 128 + d0 + r) * 2048 + s0 + c] = tile[c][r];
    }
}

// ------- Kernel 3: pooled k_cmp (roped at j*32) and v_cmp ------------------
__global__ __launch_bounds__(256) void pool_kernel(
    const float* __restrict__ k_raw, const float* __restrict__ v_raw,
    const float* __restrict__ wk_pool, const float* __restrict__ wv_pool,
    const float* __restrict__ pe, float* __restrict__ k_cmp, float* __restrict__ v_cmp)
{
    const int j = blockIdx.x;
    const int tid = threadIdx.x;
    const int kv = tid >> 7, d = tid & 127;
    float ak = 0.f, av = 0.f;
    for (int s = 0; s < 32; ++s) {
        float pev = pe[(kv * 32 + s) * 128 + d];
        float kk = k_raw[((j * 32 + s) * 2 + kv) * 128 + d] + pev;
        float vv = v_raw[((j * 32 + s) * 2 + kv) * 128 + d] + pev;
        ak += kk * wk_pool[kv * 32 + s];
        av += vv * wv_pool[kv * 32 + s];
    }
    __shared__ float sk[256];
    sk[tid] = ak;
    __syncthreads();
    int i = d & 63;
    float inv = exp2f(-(float)i * L2INV_);
    float ang = (float)(j * 32) * inv;
    float sn, cs; sincosf(ang, &sn, &cs);
    float x1 = sk[kv * 128 + i], x2 = sk[kv * 128 + i + 64];
    float outv = (d < 64) ? (x1 * cs - x2 * sn) : (x1 * sn + x2 * cs);
    k_cmp[(j * 2 + kv) * 128 + d] = outv;
    v_cmp[(j * 2 + kv) * 128 + d] = av;
}

// ------- Kernel 4: compressed attention + pw + top-8 selection (fp32) ------
__global__ __launch_bounds__(64) void cmp_sel_kernel(
    const float* __restrict__ q, const float* __restrict__ k_cmp,
    const float* __restrict__ v_cmp, float* __restrict__ o_cmp,
    unsigned long long* __restrict__ sel_mask)
{
    const int t = blockIdx.x;
    const int kv = blockIdx.y;
    const int lane = threadIdx.x;
    __shared__ float qs[4][128];
    __shared__ float ps[64];
    for (int idx = lane; idx < 512; idx += 64)
        qs[idx >> 7][idx & 127] = q[t * 1024 + kv * 512 + idx];
    __syncthreads();
    const int j = lane;
    const float4* krow = (const float4*)&k_cmp[(j * 2 + kv) * 128];
    const bool vis = (t >= j * 32 + 31);
    const bool anyvis = (t >= 31);
    float pw = 0.f;
    for (int g = 0; g < 4; ++g) {
        const float4* qrow = (const float4*)qs[g];
        float s = 0.f;
        #pragma unroll 8
        for (int ii = 0; ii < 32; ++ii) {
            float4 kk = krow[ii], qq = qrow[ii];
            s += kk.x * qq.x + kk.y * qq.y + kk.z * qq.z + kk.w * qq.w;
        }
        s *= SCALE_;
        s = vis ? s : NEGF;
        float m = wave_max(s);
        float e = expf(s - m);
        float sum = wave_sum(e);
        float p = anyvis ? (e / sum) : 0.f;
        pw += p;
        ps[lane] = p;
        __syncthreads();
        float o0 = 0.f, o1 = 0.f;
        for (int jj = 0; jj < 64; ++jj) {
            float pp = ps[jj];
            o0 += pp * v_cmp[(jj * 2 + kv) * 128 + lane];
            o1 += pp * v_cmp[(jj * 2 + kv) * 128 + lane + 64];
        }
        o_cmp[t * 1024 + kv * 512 + g * 128 + lane]      = o0;
        o_cmp[t * 1024 + kv * 512 + g * 128 + lane + 64] = o1;
        __syncthreads();
    }
    const int cur = t >> 5;
    const int curm1 = cur > 0 ? cur - 1 : 0;
    const bool forced = (j == 0) || (j == cur) || (j == curm1);
    const bool allowed = (j * 32 <= t);
    float sc = allowed ? (pw + (forced ? BIGF : 0.f)) : -1.0f;
    unsigned long long selm = 0ull;
    for (int it = 0; it < 8; ++it) {
        float bv = sc; int bi = j;
        #pragma unroll
        for (int off = 32; off >= 1; off >>= 1) {
            float ov = __shfl_xor(bv, off, 64);
            int   oi = __shfl_xor(bi, off, 64);
            if (ov > bv || (ov == bv && oi < bi)) { bv = ov; bi = oi; }
        }
        if (bv > -0.5f) selm |= (1ull << bi);
        if (j == bi) sc = -3e38f;
    }
    if (lane == 0) sel_mask[t * 2 + kv] = selm;
}

// ------- Kernel 5: sliding-window attention, bf16 MFMA flash ---------------
__global__ __launch_bounds__(256) void swa_kernel(
    const short* __restrict__ qb, const short* __restrict__ krb,
    const short* __restrict__ vT, float* __restrict__ out)
{
    const int t0 = blockIdx.x * 32;
    const int kv = blockIdx.y;
    const int w  = threadIdx.x >> 6;
    const int l  = threadIdx.x & 63;
    const int l16 = l & 15, g4 = l >> 4;
    __shared__ __align__(16) short plds[4][32][40];

    short8 qf[2][4];
    #pragma unroll
    for (int mt = 0; mt < 2; ++mt)
        #pragma unroll
        for (int ks = 0; ks < 4; ++ks)
            qf[mt][ks] = *(const short8*)(qb + ((size_t)(t0 + mt * 16 + l16) * 8 + kv * 4 + w) * 128 + ks * 32 + g4 * 8);

    f32x4 acc[2][8];
    #pragma unroll
    for (int mt = 0; mt < 2; ++mt)
        #pragma unroll
        for (int nt = 0; nt < 8; ++nt) acc[mt][nt] = (f32x4)0.f;
    float m_r[2][4], l_r[2][4];
    #pragma unroll
    for (int mt = 0; mt < 2; ++mt)
        #pragma unroll
        for (int r = 0; r < 4; ++r) { m_r[mt][r] = NEGF; l_r[mt][r] = 0.f; }

    const int sLo = (t0 >= 256) ? (t0 - 256) : 0;
    for (int s0 = sLo; s0 <= t0 + 31; s0 += 32) {
        f32x4 sc[2][2];
        #pragma unroll
        for (int mt = 0; mt < 2; ++mt)
            #pragma unroll
            for (int nt = 0; nt < 2; ++nt) sc[mt][nt] = (f32x4)0.f;
        #pragma unroll
        for (int nt = 0; nt < 2; ++nt) {
            short8 kf[4];
            #pragma unroll
            for (int ks = 0; ks < 4; ++ks)
                kf[ks] = *(const short8*)(krb + ((size_t)(s0 + nt * 16 + l16) * 2 + kv) * 128 + ks * 32 + g4 * 8);
            #pragma unroll
            for (int mt = 0; mt < 2; ++mt)
                #pragma unroll
                for (int ks = 0; ks < 4; ++ks)
                    sc[mt][nt] = __builtin_amdgcn_mfma_f32_16x16x32_bf16(qf[mt][ks], kf[ks], sc[mt][nt], 0, 0, 0);
        }
        #pragma unroll
        for (int mt = 0; mt < 2; ++mt) {
            #pragma unroll
            for (int r = 0; r < 4; ++r) {
                const int tq = t0 + mt * 16 + g4 * 4 + r;
                const int sk0 = s0 + l16, sk1 = s0 + 16 + l16;
                const bool v0 = (sk0 <= tq) && (sk0 >= tq - 256);
                const bool v1 = (sk1 <= tq) && (sk1 >= tq - 256);
                float s0v = v0 ? sc[mt][0][r] * SCALE_ : NEGF;
                float s1v = v1 ? sc[mt][1][r] * SCALE_ : NEGF;
                float mx = grp16_max(fmaxf(s0v, s1v));
                float mnew = fmaxf(m_r[mt][r], mx);
                float al = __expf(m_r[mt][r] - mnew);
                float p0 = v0 ? __expf(s0v - mnew) : 0.f;
                float p1 = v1 ? __expf(s1v - mnew) : 0.f;
                float rs = grp16_sum(p0 + p1);
                l_r[mt][r] = l_r[mt][r] * al + rs;
                m_r[mt][r] = mnew;
                #pragma unroll
                for (int nt = 0; nt < 8; ++nt) acc[mt][nt][r] *= al;
                plds[w][mt * 16 + g4 * 4 + r][l16]      = bf16_of(p0);
                plds[w][mt * 16 + g4 * 4 + r][16 + l16] = bf16_of(p1);
            }
        }
        short8 pa[2];
        #pragma unroll
        for (int mt = 0; mt < 2; ++mt)
            pa[mt] = *(const short8*)(&plds[w][mt * 16 + l16][g4 * 8]);
        #pragma unroll
        for (int nt = 0; nt < 8; ++nt) {
            short8 vf = *(const short8*)(vT + ((size_t)kv * 128 + nt * 16 + l16) * 2048 + s0 + g4 * 8);
            #pragma unroll
            for (int mt = 0; mt < 2; ++mt)
                acc[mt][nt] = __builtin_amdgcn_mfma_f32_16x16x32_bf16(pa[mt], vf, acc[mt][nt], 0, 0, 0);
        }
    }
    #pragma unroll
    for (int mt = 0; mt < 2; ++mt)
        #pragma unroll
        for (int r = 0; r < 4; ++r) {
            const int tq = t0 + mt * 16 + g4 * 4 + r;
            const float rl = 1.0f / l_r[mt][r];
            #pragma unroll
            for (int nt = 0; nt < 8; ++nt)
                out[(size_t)tq * 1024 + (kv * 4 + w) * 128 + nt * 16 + l16] = acc[mt][nt][r] * rl;
        }
}

// ------- Kernel 6: selected attention (union of 16 queries) + combine ------
__global__ __launch_bounds__(256) void slc_kernel(
    const short* __restrict__ qb, const short* __restrict__ krb,
    const short* __restrict__ vT, const unsigned long long* __restrict__ sel,
    const float* __restrict__ gsig, const float* __restrict__ o_cmp,
    float* __restrict__ out)
{
    const int t0 = blockIdx.x * 16;
    const int kv = blockIdx.y;
    const int w  = threadIdx.x >> 6;
    const int l  = threadIdx.x & 63;
    const int l16 = l & 15, g4 = l >> 4;
    __shared__ __align__(16) short plds[4][16][40];
    __shared__ unsigned long long qm[16];
    __shared__ unsigned char blist[64];
    __shared__ int nbs;
    if (threadIdx.x < 16) qm[threadIdx.x] = sel[(size_t)(t0 + threadIdx.x) * 2 + kv];
    __syncthreads();
    if (threadIdx.x == 0) {
        unsigned long long u = 0ull;
        #pragma unroll
        for (int i = 0; i < 16; ++i) u |= qm[i];
        int n = 0;
        while (u) { blist[n++] = (unsigned char)(__ffsll((long long)u) - 1); u &= u - 1; }
        nbs = n;
    }
    __syncthreads();

    short8 qf[4];
    #pragma unroll
    for (int ks = 0; ks < 4; ++ks)
        qf[ks] = *(const short8*)(qb + ((size_t)(t0 + l16) * 8 + kv * 4 + w) * 128 + ks * 32 + g4 * 8);

    f32x4 acc[8];
    #pragma unroll
    for (int nt = 0; nt < 8; ++nt) acc[nt] = (f32x4)0.f;
    float m_r[4], l_r[4];
    #pragma unroll
    for (int r = 0; r < 4; ++r) { m_r[r] = NEGF; l_r[r] = 0.f; }

    const int nb = nbs;
    for (int bi = 0; bi < nb; ++bi) {
        const int j = blist[bi];
        const int s0 = j * 32;
        f32x4 sc[2];
        sc[0] = (f32x4)0.f; sc[1] = (f32x4)0.f;
        #pragma unroll
        for (int nt = 0; nt < 2; ++nt) {
            short8 kf[4];
            #pragma unroll
            for (int ks = 0; ks < 4; ++ks)
                kf[ks] = *(const short8*)(krb + ((size_t)(s0 + nt * 16 + l16) * 2 + kv) * 128 + ks * 32 + g4 * 8);
            #pragma unroll
            for (int ks = 0; ks < 4; ++ks)
                sc[nt] = __builtin_amdgcn_mfma_f32_16x16x32_bf16(qf[ks], kf[ks], sc[nt], 0, 0, 0);
        }
        #pragma unroll
        for (int r = 0; r < 4; ++r) {
            const int ql = g4 * 4 + r;
            const int tq = t0 + ql;
            const bool inmask = (qm[ql] >> j) & 1ull;
            const int sk0 = s0 + l16, sk1 = s0 + 16 + l16;
            const bool v0 = inmask && (sk0 <= tq);
            const bool v1 = inmask && (sk1 <= tq);
            float s0v = v0 ? sc[0][r] * SCALE_ : NEGF;
            float s1v = v1 ? sc[1][r] * SCALE_ : NEGF;
            float mx = grp16_max(fmaxf(s0v, s1v));
            float mnew = fmaxf(m_r[r], mx);
            float al = __expf(m_r[r] - mnew);
            float p0 = v0 ? __expf(s0v - mnew) : 0.f;
            float p1 = v1 ? __expf(s1v - mnew) : 0.f;
            float rs = grp16_sum(p0 + p1);
            l_r[r] = l_r[r] * al + rs;
            m_r[r] = mnew;
            #pragma unroll
            for (int nt = 0; nt < 8; ++nt) acc[nt][r] *= al;
            plds[w][ql][l16]      = bf16_of(p0);
            plds[w][ql][16 + l16] = bf16_of(p1);
        }
        short8 pa = *(const short8*)(&plds[w][l16][g4 * 8]);
        #pragma unroll
        for (int nt = 0; nt < 8; ++nt) {
            short8 vf = *(const short8*)(vT + ((size_t)kv * 128 + nt * 16 + l16) * 2048 + s0 + g4 * 8);
            acc[nt] = __builtin_amdgcn_mfma_f32_16x16x32_bf16(pa, vf, acc[nt], 0, 0, 0);
        }
    }
    #pragma unroll
    for (int r = 0; r < 4; ++r) {
        const int tq = t0 + g4 * 4 + r;
        const float rl = 1.0f / l_r[r];
        const float gc = gsig[tq * 24 + kv * 12 + w * 3 + 0];
        const float gs = gsig[tq * 24 + kv * 12 + w * 3 + 1];
        const float gw = gsig[tq * 24 + kv * 12 + w * 3 + 2];
        #pragma unroll
        for (int nt = 0; nt < 8; ++nt) {
            const size_t idx = (size_t)tq * 1024 + (kv * 4 + w) * 128 + nt * 16 + l16;
            out[idx] = gc * o_cmp[idx] + gs * (acc[nt][r] * rl) + gw * out[idx];
        }
    }
}

extern "C" void kernel_launch(void* const* d_in, const int* in_sizes, int n_in,
                              void* d_out, int out_size, void* d_ws, size_t ws_size,
                              hipStream_t stream)
{
    const float* x       = (const float*)d_in[0];
    const float* Wq      = (const float*)d_in[1];
    const float* Wk      = (const float*)d_in[2];
    const float* Wv      = (const float*)d_in[3];
    const float* Wg      = (const float*)d_in[4];
    const float* wk_pool = (const float*)d_in[5];
    const float* wv_pool = (const float*)d_in[6];
    const float* pe      = (const float*)d_in[7];
    float* out = (float*)d_out;
    float* ws  = (float*)d_ws;

    // ---- workspace layout (floats); total ~27.9 MB ----
    float* q     = ws;                         // 2,097,152
    float* k_raw = q + 2097152;                //   524,288
    float* v     = k_raw + 524288;             //   524,288
    float* gsig  = v + 524288;                 //    49,152
    float* k_cmp = gsig + 49152;               //    16,384
    float* v_cmp = k_cmp + 16384;              //    16,384
    unsigned long long* sel = (unsigned long long*)(v_cmp + 16384); // 8,192 f
    float* o_cmp = (float*)sel + 8192;         // 2,097,152
    // xhi/xlo alias o_cmp (dead before cmp_sel writes o_cmp)
    short* xhi   = (short*)o_cmp;              // 2,097,152 shorts
    short* xlo   = xhi + 2097152;              // 2,097,152 shorts
    short* qb    = (short*)(o_cmp + 2097152);  // 2,097,152 shorts
    short* krb   = qb + 2097152;               //   524,288 shorts
    short* vT    = krb + 524288;               //   524,288 shorts
    // wthi/wtlo alias qb..(vT+pad) (dead before rope_conv/vtrans write)
    short* wthi  = qb;                         // 1,638,400 shorts
    short* wtlo  = wthi + 1638400;             // 1,638,400 shorts (needs 131,072-short pad past vT)

    hipLaunchKernelGGL(xconv_kernel, dim3(2048), dim3(256), 0, stream, x, xhi, xlo);
    hipLaunchKernelGGL(wconv_kernel, dim3(50, 32), dim3(256), 0, stream,
                       Wq, Wk, Wv, Wg, wthi, wtlo);
    hipLaunchKernelGGL(proj_mfma_kernel, dim3(25, 16), dim3(512), 0, stream,
                       xhi, xlo, wthi, wtlo, q, k_raw, v, gsig);
    hipLaunchKernelGGL(rope_conv_kernel, dim3(2048, 10), dim3(64), 0, stream,
                       q, k_raw, qb, krb);
    hipLaunchKernelGGL(vtrans_kernel, dim3(64, 4, 2), dim3(256), 0, stream,
                       v, vT);
    hipLaunchKernelGGL(pool_kernel, dim3(64), dim3(256), 0, stream,
                       k_raw, v, wk_pool, wv_pool, pe, k_cmp, v_cmp);
    hipLaunchKernelGGL(cmp_sel_kernel, dim3(2048, 2), dim3(64), 0, stream,
                       q, k_cmp, v_cmp, o_cmp, sel);
    hipLaunchKernelGGL(swa_kernel, dim3(64, 2), dim3(256), 0, stream,
                       qb, krb, vT, out);
    hipLaunchKernelGGL(slc_kernel, dim3(128, 2), dim3(256), 0, stream,
                       qb, krb, vT, sel, gsig, o_cmp, out);
}

// Round 4
// 268.326 us; speedup vs baseline: 3.1152x; 1.3400x over previous
//
#include <hip/hip_runtime.h>
#include <math.h>

#define NEGF  (-1e30f)
#define BIGF  (1000000.0f)
#define SCALE_ (0.08838834764831845f)   // 1/sqrt(128)
#define L2INV_ (0.20762050593046014f)   // log2(10000)/64

typedef __attribute__((ext_vector_type(4))) float f32x4;
typedef __attribute__((ext_vector_type(8))) short short8;
typedef __attribute__((ext_vector_type(4))) short short4v;
typedef __attribute__((ext_vector_type(8))) _Float16 half8;

#define GLDS16(gp, lp) __builtin_amdgcn_global_load_lds( \
    (const __attribute__((address_space(1))) void*)(gp), \
    (__attribute__((address_space(3))) void*)(lp), 16, 0, 0)

__device__ __forceinline__ float wave_max(float v) {
    #pragma unroll
    for (int off = 32; off >= 1; off >>= 1) v = fmaxf(v, __shfl_xor(v, off, 64));
    return v;
}
__device__ __forceinline__ float wave_sum(float v) {
    #pragma unroll
    for (int off = 32; off >= 1; off >>= 1) v += __shfl_xor(v, off, 64);
    return v;
}
__device__ __forceinline__ float grp16_max(float v) {
    #pragma unroll
    for (int off = 8; off >= 1; off >>= 1) v = fmaxf(v, __shfl_xor(v, off, 64));
    return v;
}
__device__ __forceinline__ float grp16_sum(float v) {
    #pragma unroll
    for (int off = 8; off >= 1; off >>= 1) v += __shfl_xor(v, off, 64);
    return v;
}
__device__ __forceinline__ short bf16_of(float f) {
    union { float f; unsigned u; } x; x.f = f;
    unsigned r = x.u + 0x7fffu + ((x.u >> 16) & 1u);
    return (short)(r >> 16);
}
__device__ __forceinline__ short f16_of(float f) {
    _Float16 h = (_Float16)f;
    union { _Float16 h; short s; } u; u.h = h;
    return u.s;
}
__device__ __forceinline__ float f32_of_f16(short s) {
    union { _Float16 h; short s; } u; u.s = s;
    return (float)u.h;
}

// -------- Kernel 0a: x (fp32) -> xhi/xlo fp16 split ------------------------
__global__ __launch_bounds__(256) void xconv_kernel(
    const float* __restrict__ x, short* __restrict__ xhi, short* __restrict__ xlo)
{
    const int i = blockIdx.x * 1024 + threadIdx.x * 4;
    float4 f = *(const float4*)(x + i);
    short4v hi, lo;
    float fv[4] = {f.x, f.y, f.z, f.w};
    #pragma unroll
    for (int c = 0; c < 4; ++c) {
        short h = f16_of(fv[c]);
        hi[c] = h;
        lo[c] = f16_of(fv[c] - f32_of_f16(h));
    }
    *(short4v*)(xhi + i) = hi;
    *(short4v*)(xlo + i) = lo;
}

// -------- Kernel 0b: W's -> WT fp16 split, transposed [1600][1024] ---------
__global__ __launch_bounds__(256) void wconv_kernel(
    const float* __restrict__ Wq, const float* __restrict__ Wk,
    const float* __restrict__ Wv, const float* __restrict__ Wg,
    short* __restrict__ wthi, short* __restrict__ wtlo)
{
    __shared__ float tile[32][33];
    const int ct = blockIdx.x, kt = blockIdx.y;
    const int c = threadIdx.x & 31, r0 = threadIdx.x >> 5;
    #pragma unroll
    for (int rr = 0; rr < 32; rr += 8) {
        int k = kt * 32 + r0 + rr;
        int gc = ct * 32 + c;
        float val;
        if (gc < 1024)      val = Wq[k * 1024 + gc];
        else if (gc < 1280) val = Wk[k * 256 + gc - 1024];
        else if (gc < 1536) val = Wv[k * 256 + gc - 1280];
        else if (gc < 1560) val = Wg[k * 24 + gc - 1536];
        else                val = 0.f;
        tile[r0 + rr][c] = val;
    }
    __syncthreads();
    #pragma unroll
    for (int rr = 0; rr < 32; rr += 8) {
        int col = ct * 32 + r0 + rr;
        int k = kt * 32 + c;
        float val = tile[c][r0 + rr];
        short hi = f16_of(val);
        short lo = f16_of(val - f32_of_f16(hi));
        wthi[(size_t)col * 1024 + k] = hi;
        wtlo[(size_t)col * 1024 + k] = lo;
    }
}

// -------- Kernel 1: projections via split-fp16 MFMA, LDS-staged ------------
// BM=128 x BN=64 tile, BK=64, 8 waves of 32x32, global_load_lds + XOR swizzle.
__global__ __launch_bounds__(512) void proj_mfma_kernel(
    const short* __restrict__ xhi, const short* __restrict__ xlo,
    const short* __restrict__ wthi, const short* __restrict__ wtlo,
    float* __restrict__ q, float* __restrict__ k_raw,
    float* __restrict__ v, float* __restrict__ gsig)
{
    // LDS (shorts): Ahi[0,8192) Alo[8192,16384) Bhi[16384,20480) Blo[20480,24576)
    __shared__ __align__(16) short lds[24576];
    const int cb = blockIdx.x;             // 25 col tiles of 64
    const int tb = blockIdx.y;             // 16 row tiles of 128
    const int w = threadIdx.x >> 6;        // 0..7
    const int l = threadIdx.x & 63;
    const int l16 = l & 15, g4 = l >> 4;
    const int wm = w >> 1, wn = w & 1;     // wave -> 32x32 sub-tile
    const int row0 = tb * 128, col0 = cb * 64;

    // staging source pointers (pre-swizzled global addresses; LDS dest linear)
    const short* pAhi[2]; const short* pAlo[2];
    #pragma unroll
    for (int j = 0; j < 2; ++j) {
        int b = (2 * w + j) * 1024 + l * 16;       // byte off in 16KB A comp
        int row = b >> 7;                           // 128 B per row
        int kb = (b & 127) ^ ((row & 7) << 4);      // inverse-swizzled source
        pAhi[j] = xhi + (size_t)(row0 + row) * 1024 + (kb >> 1);
        pAlo[j] = xlo + (size_t)(row0 + row) * 1024 + (kb >> 1);
    }
    const short* pBhi; const short* pBlo;
    {
        int b = w * 1024 + l * 16;                 // byte off in 8KB B comp
        int col = b >> 7;
        int kb = (b & 127) ^ ((col & 7) << 4);
        pBhi = wthi + (size_t)(col0 + col) * 1024 + (kb >> 1);
        pBlo = wtlo + (size_t)(col0 + col) * 1024 + (kb >> 1);
    }

    f32x4 acc[2][2];
    #pragma unroll
    for (int mt = 0; mt < 2; ++mt)
        #pragma unroll
        for (int nt = 0; nt < 2; ++nt) acc[mt][nt] = (f32x4)0.f;

    for (int k0 = 0; k0 < 1024; k0 += 64) {
        GLDS16(pAhi[0] + k0, &lds[(2 * w + 0) * 512]);
        GLDS16(pAhi[1] + k0, &lds[(2 * w + 1) * 512]);
        GLDS16(pAlo[0] + k0, &lds[8192 + (2 * w + 0) * 512]);
        GLDS16(pAlo[1] + k0, &lds[8192 + (2 * w + 1) * 512]);
        GLDS16(pBhi + k0,    &lds[16384 + w * 512]);
        GLDS16(pBlo + k0,    &lds[20480 + w * 512]);
        __syncthreads();
        #pragma unroll
        for (int ksub = 0; ksub < 2; ++ksub) {
            half8 ah[2], al[2], bh[2], bl[2];
            #pragma unroll
            for (int mt = 0; mt < 2; ++mt) {
                int row = wm * 32 + mt * 16 + l16;
                int kb = (ksub * 64 + g4 * 16) ^ ((row & 7) << 4);
                ah[mt] = *(const half8*)(const void*)&lds[row * 64 + (kb >> 1)];
                al[mt] = *(const half8*)(const void*)&lds[8192 + row * 64 + (kb >> 1)];
            }
            #pragma unroll
            for (int nt = 0; nt < 2; ++nt) {
                int col = wn * 32 + nt * 16 + l16;
                int kb = (ksub * 64 + g4 * 16) ^ ((col & 7) << 4);
                bh[nt] = *(const half8*)(const void*)&lds[16384 + col * 64 + (kb >> 1)];
                bl[nt] = *(const half8*)(const void*)&lds[20480 + col * 64 + (kb >> 1)];
            }
            #pragma unroll
            for (int mt = 0; mt < 2; ++mt)
                #pragma unroll
                for (int nt = 0; nt < 2; ++nt) {
                    acc[mt][nt] = __builtin_amdgcn_mfma_f32_16x16x32_f16(ah[mt], bh[nt], acc[mt][nt], 0, 0, 0);
                    acc[mt][nt] = __builtin_amdgcn_mfma_f32_16x16x32_f16(ah[mt], bl[nt], acc[mt][nt], 0, 0, 0);
                    acc[mt][nt] = __builtin_amdgcn_mfma_f32_16x16x32_f16(al[mt], bh[nt], acc[mt][nt], 0, 0, 0);
                }
        }
        __syncthreads();
    }
    #pragma unroll
    for (int mt = 0; mt < 2; ++mt) {
        #pragma unroll
        for (int r = 0; r < 4; ++r) {
            const int tt = row0 + wm * 32 + mt * 16 + g4 * 4 + r;
            #pragma unroll
            for (int nt = 0; nt < 2; ++nt) {
                const int cg = col0 + wn * 32 + nt * 16 + l16;
                const float val = acc[mt][nt][r];
                if (cg < 1024)      q[(size_t)tt * 1024 + cg] = val;
                else if (cg < 1280) k_raw[(size_t)tt * 256 + cg - 1024] = val;
                else if (cg < 1536) v[(size_t)tt * 256 + cg - 1280] = val;
                else if (cg < 1560) gsig[(size_t)tt * 24 + cg - 1536] = 1.0f / (1.0f + expf(-val));
            }
        }
    }
}

// ------ Kernel 2: RoPE on q (in place) and k, plus bf16 copies -------------
__global__ __launch_bounds__(256) void rope_conv_kernel(
    float* __restrict__ q, const float* __restrict__ k_raw,
    short* __restrict__ qb, short* __restrict__ krb)
{
    const int t = blockIdx.x * 4 + (threadIdx.x >> 6);
    const int h = blockIdx.y;          // 0..7 q heads, 8..9 kv heads
    const int i = threadIdx.x & 63;    // 0..63
    float inv = exp2f(-(float)i * L2INV_);
    float ang = (float)t * inv;
    float sn, cs;
    sincosf(ang, &sn, &cs);
    if (h < 8) {
        float* p = q + t * 1024 + h * 128;
        float x1 = p[i], x2 = p[i + 64];
        float r1 = x1 * cs - x2 * sn;
        float r2 = x1 * sn + x2 * cs;
        p[i] = r1; p[i + 64] = r2;
        qb[t * 1024 + h * 128 + i]      = bf16_of(r1);
        qb[t * 1024 + h * 128 + i + 64] = bf16_of(r2);
    } else {
        const float* s = k_raw + t * 256 + (h - 8) * 128;
        float x1 = s[i], x2 = s[i + 64];
        krb[t * 256 + (h - 8) * 128 + i]      = bf16_of(x1 * cs - x2 * sn);
        krb[t * 256 + (h - 8) * 128 + i + 64] = bf16_of(x1 * sn + x2 * cs);
    }
}

// ------ Kernel 2b: v (fp32 [s][kv][d]) -> vT bf16 [kv][d][s] ---------------
__global__ __launch_bounds__(256) void vtrans_kernel(
    const float* __restrict__ v, short* __restrict__ vT)
{
    __shared__ short tile[32][33];
    const int s0 = blockIdx.x * 32, d0 = blockIdx.y * 32, kv = blockIdx.z;
    const int c = threadIdx.x & 31, r0 = threadIdx.x >> 5;
    #pragma unroll
    for (int rr = 0; rr < 32; rr += 8) {
        int r = r0 + rr;
        tile[r][c] = bf16_of(v[((size_t)(s0 + r) * 2 + kv) * 128 + d0 + c]);
    }
    __syncthreads();
    #pragma unroll
    for (int rr = 0; rr < 32; rr += 8) {
        int r = r0 + rr;
        vT[((size_t)kv * 128 + d0 + r) * 2048 + s0 + c] = tile[c][r];
    }
}

// ------- Kernel 3: pooled k_cmp (roped at j*32) and v_cmp ------------------
__global__ __launch_bounds__(256) void pool_kernel(
    const float* __restrict__ k_raw, const float* __restrict__ v_raw,
    const float* __restrict__ wk_pool, const float* __restrict__ wv_pool,
    const float* __restrict__ pe, float* __restrict__ k_cmp, float* __restrict__ v_cmp)
{
    const int j = blockIdx.x;
    const int tid = threadIdx.x;
    const int kv = tid >> 7, d = tid & 127;
    float ak = 0.f, av = 0.f;
    for (int s = 0; s < 32; ++s) {
        float pev = pe[(kv * 32 + s) * 128 + d];
        float kk = k_raw[((j * 32 + s) * 2 + kv) * 128 + d] + pev;
        float vv = v_raw[((j * 32 + s) * 2 + kv) * 128 + d] + pev;
        ak += kk * wk_pool[kv * 32 + s];
        av += vv * wv_pool[kv * 32 + s];
    }
    __shared__ float sk[256];
    sk[tid] = ak;
    __syncthreads();
    int i = d & 63;
    float inv = exp2f(-(float)i * L2INV_);
    float ang = (float)(j * 32) * inv;
    float sn, cs; sincosf(ang, &sn, &cs);
    float x1 = sk[kv * 128 + i], x2 = sk[kv * 128 + i + 64];
    float outv = (d < 64) ? (x1 * cs - x2 * sn) : (x1 * sn + x2 * cs);
    k_cmp[(j * 2 + kv) * 128 + d] = outv;
    v_cmp[(j * 2 + kv) * 128 + d] = av;
}

// ------- Kernel 4: compressed attention + pw + top-8 selection (fp32) ------
__global__ __launch_bounds__(64) void cmp_sel_kernel(
    const float* __restrict__ q, const float* __restrict__ k_cmp,
    const float* __restrict__ v_cmp, float* __restrict__ o_cmp,
    unsigned long long* __restrict__ sel_mask)
{
    const int t = blockIdx.x;
    const int kv = blockIdx.y;
    const int lane = threadIdx.x;
    __shared__ float qs[4][128];
    __shared__ float ps[64];
    for (int idx = lane; idx < 512; idx += 64)
        qs[idx >> 7][idx & 127] = q[t * 1024 + kv * 512 + idx];
    __syncthreads();
    const int j = lane;
    const float4* krow = (const float4*)&k_cmp[(j * 2 + kv) * 128];
    const bool vis = (t >= j * 32 + 31);
    const bool anyvis = (t >= 31);
    float pw = 0.f;
    for (int g = 0; g < 4; ++g) {
        const float4* qrow = (const float4*)qs[g];
        float s = 0.f;
        #pragma unroll 8
        for (int ii = 0; ii < 32; ++ii) {
            float4 kk = krow[ii], qq = qrow[ii];
            s += kk.x * qq.x + kk.y * qq.y + kk.z * qq.z + kk.w * qq.w;
        }
        s *= SCALE_;
        s = vis ? s : NEGF;
        float m = wave_max(s);
        float e = expf(s - m);
        float sum = wave_sum(e);
        float p = anyvis ? (e / sum) : 0.f;
        pw += p;
        ps[lane] = p;
        __syncthreads();
        float o0 = 0.f, o1 = 0.f;
        for (int jj = 0; jj < 64; ++jj) {
            float pp = ps[jj];
            o0 += pp * v_cmp[(jj * 2 + kv) * 128 + lane];
            o1 += pp * v_cmp[(jj * 2 + kv) * 128 + lane + 64];
        }
        o_cmp[t * 1024 + kv * 512 + g * 128 + lane]      = o0;
        o_cmp[t * 1024 + kv * 512 + g * 128 + lane + 64] = o1;
        __syncthreads();
    }
    const int cur = t >> 5;
    const int curm1 = cur > 0 ? cur - 1 : 0;
    const bool forced = (j == 0) || (j == cur) || (j == curm1);
    const bool allowed = (j * 32 <= t);
    float sc = allowed ? (pw + (forced ? BIGF : 0.f)) : -1.0f;
    unsigned long long selm = 0ull;
    for (int it = 0; it < 8; ++it) {
        float bv = sc; int bi = j;
        #pragma unroll
        for (int off = 32; off >= 1; off >>= 1) {
            float ov = __shfl_xor(bv, off, 64);
            int   oi = __shfl_xor(bi, off, 64);
            if (ov > bv || (ov == bv && oi < bi)) { bv = ov; bi = oi; }
        }
        if (bv > -0.5f) selm |= (1ull << bi);
        if (j == bi) sc = -3e38f;
    }
    if (lane == 0) sel_mask[t * 2 + kv] = selm;
}

// ------- Kernel 5: sliding-window attention, bf16 MFMA flash ---------------
__global__ __launch_bounds__(256) void swa_kernel(
    const short* __restrict__ qb, const short* __restrict__ krb,
    const short* __restrict__ vT, float* __restrict__ out)
{
    const int t0 = blockIdx.x * 32;
    const int kv = blockIdx.y;
    const int w  = threadIdx.x >> 6;
    const int l  = threadIdx.x & 63;
    const int l16 = l & 15, g4 = l >> 4;
    __shared__ __align__(16) short plds[4][32][40];

    short8 qf[2][4];
    #pragma unroll
    for (int mt = 0; mt < 2; ++mt)
        #pragma unroll
        for (int ks = 0; ks < 4; ++ks)
            qf[mt][ks] = *(const short8*)(qb + ((size_t)(t0 + mt * 16 + l16) * 8 + kv * 4 + w) * 128 + ks * 32 + g4 * 8);

    f32x4 acc[2][8];
    #pragma unroll
    for (int mt = 0; mt < 2; ++mt)
        #pragma unroll
        for (int nt = 0; nt < 8; ++nt) acc[mt][nt] = (f32x4)0.f;
    float m_r[2][4], l_r[2][4];
    #pragma unroll
    for (int mt = 0; mt < 2; ++mt)
        #pragma unroll
        for (int r = 0; r < 4; ++r) { m_r[mt][r] = NEGF; l_r[mt][r] = 0.f; }

    const int sLo = (t0 >= 256) ? (t0 - 256) : 0;
    for (int s0 = sLo; s0 <= t0 + 31; s0 += 32) {
        f32x4 sc[2][2];
        #pragma unroll
        for (int mt = 0; mt < 2; ++mt)
            #pragma unroll
            for (int nt = 0; nt < 2; ++nt) sc[mt][nt] = (f32x4)0.f;
        #pragma unroll
        for (int nt = 0; nt < 2; ++nt) {
            short8 kf[4];
            #pragma unroll
            for (int ks = 0; ks < 4; ++ks)
                kf[ks] = *(const short8*)(krb + ((size_t)(s0 + nt * 16 + l16) * 2 + kv) * 128 + ks * 32 + g4 * 8);
            #pragma unroll
            for (int mt = 0; mt < 2; ++mt)
                #pragma unroll
                for (int ks = 0; ks < 4; ++ks)
                    sc[mt][nt] = __builtin_amdgcn_mfma_f32_16x16x32_bf16(qf[mt][ks], kf[ks], sc[mt][nt], 0, 0, 0);
        }
        #pragma unroll
        for (int mt = 0; mt < 2; ++mt) {
            #pragma unroll
            for (int r = 0; r < 4; ++r) {
                const int tq = t0 + mt * 16 + g4 * 4 + r;
                const int sk0 = s0 + l16, sk1 = s0 + 16 + l16;
                const bool v0 = (sk0 <= tq) && (sk0 >= tq - 256);
                const bool v1 = (sk1 <= tq) && (sk1 >= tq - 256);
                float s0v = v0 ? sc[mt][0][r] * SCALE_ : NEGF;
                float s1v = v1 ? sc[mt][1][r] * SCALE_ : NEGF;
                float mx = grp16_max(fmaxf(s0v, s1v));
                float mnew = fmaxf(m_r[mt][r], mx);
                float al = __expf(m_r[mt][r] - mnew);
                float p0 = v0 ? __expf(s0v - mnew) : 0.f;
                float p1 = v1 ? __expf(s1v - mnew) : 0.f;
                float rs = grp16_sum(p0 + p1);
                l_r[mt][r] = l_r[mt][r] * al + rs;
                m_r[mt][r] = mnew;
                #pragma unroll
                for (int nt = 0; nt < 8; ++nt) acc[mt][nt][r] *= al;
                plds[w][mt * 16 + g4 * 4 + r][l16]      = bf16_of(p0);
                plds[w][mt * 16 + g4 * 4 + r][16 + l16] = bf16_of(p1);
            }
        }
        short8 pa[2];
        #pragma unroll
        for (int mt = 0; mt < 2; ++mt)
            pa[mt] = *(const short8*)(&plds[w][mt * 16 + l16][g4 * 8]);
        #pragma unroll
        for (int nt = 0; nt < 8; ++nt) {
            short8 vf = *(const short8*)(vT + ((size_t)kv * 128 + nt * 16 + l16) * 2048 + s0 + g4 * 8);
            #pragma unroll
            for (int mt = 0; mt < 2; ++mt)
                acc[mt][nt] = __builtin_amdgcn_mfma_f32_16x16x32_bf16(pa[mt], vf, acc[mt][nt], 0, 0, 0);
        }
    }
    #pragma unroll
    for (int mt = 0; mt < 2; ++mt)
        #pragma unroll
        for (int r = 0; r < 4; ++r) {
            const int tq = t0 + mt * 16 + g4 * 4 + r;
            const float rl = 1.0f / l_r[mt][r];
            #pragma unroll
            for (int nt = 0; nt < 8; ++nt)
                out[(size_t)tq * 1024 + (kv * 4 + w) * 128 + nt * 16 + l16] = acc[mt][nt][r] * rl;
        }
}

// ------- Kernel 6: selected attention (union of 16 queries) + combine ------
__global__ __launch_bounds__(256) void slc_kernel(
    const short* __restrict__ qb, const short* __restrict__ krb,
    const short* __restrict__ vT, const unsigned long long* __restrict__ sel,
    const float* __restrict__ gsig, const float* __restrict__ o_cmp,
    float* __restrict__ out)
{
    const int t0 = blockIdx.x * 16;
    const int kv = blockIdx.y;
    const int w  = threadIdx.x >> 6;
    const int l  = threadIdx.x & 63;
    const int l16 = l & 15, g4 = l >> 4;
    __shared__ __align__(16) short plds[4][16][40];
    __shared__ unsigned long long qm[16];
    __shared__ unsigned char blist[64];
    __shared__ int nbs;
    if (threadIdx.x < 16) qm[threadIdx.x] = sel[(size_t)(t0 + threadIdx.x) * 2 + kv];
    __syncthreads();
    if (threadIdx.x == 0) {
        unsigned long long u = 0ull;
        #pragma unroll
        for (int i = 0; i < 16; ++i) u |= qm[i];
        int n = 0;
        while (u) { blist[n++] = (unsigned char)(__ffsll((long long)u) - 1); u &= u - 1; }
        nbs = n;
    }
    __syncthreads();

    short8 qf[4];
    #pragma unroll
    for (int ks = 0; ks < 4; ++ks)
        qf[ks] = *(const short8*)(qb + ((size_t)(t0 + l16) * 8 + kv * 4 + w) * 128 + ks * 32 + g4 * 8);

    f32x4 acc[8];
    #pragma unroll
    for (int nt = 0; nt < 8; ++nt) acc[nt] = (f32x4)0.f;
    float m_r[4], l_r[4];
    #pragma unroll
    for (int r = 0; r < 4; ++r) { m_r[r] = NEGF; l_r[r] = 0.f; }

    const int nb = nbs;
    for (int bi = 0; bi < nb; ++bi) {
        const int j = blist[bi];
        const int s0 = j * 32;
        f32x4 sc[2];
        sc[0] = (f32x4)0.f; sc[1] = (f32x4)0.f;
        #pragma unroll
        for (int nt = 0; nt < 2; ++nt) {
            short8 kf[4];
            #pragma unroll
            for (int ks = 0; ks < 4; ++ks)
                kf[ks] = *(const short8*)(krb + ((size_t)(s0 + nt * 16 + l16) * 2 + kv) * 128 + ks * 32 + g4 * 8);
            #pragma unroll
            for (int ks = 0; ks < 4; ++ks)
                sc[nt] = __builtin_amdgcn_mfma_f32_16x16x32_bf16(qf[ks], kf[ks], sc[nt], 0, 0, 0);
        }
        #pragma unroll
        for (int r = 0; r < 4; ++r) {
            const int ql = g4 * 4 + r;
            const int tq = t0 + ql;
            const bool inmask = (qm[ql] >> j) & 1ull;
            const int sk0 = s0 + l16, sk1 = s0 + 16 + l16;
            const bool v0 = inmask && (sk0 <= tq);
            const bool v1 = inmask && (sk1 <= tq);
            float s0v = v0 ? sc[0][r] * SCALE_ : NEGF;
            float s1v = v1 ? sc[1][r] * SCALE_ : NEGF;
            float mx = grp16_max(fmaxf(s0v, s1v));
            float mnew = fmaxf(m_r[r], mx);
            float al = __expf(m_r[r] - mnew);
            float p0 = v0 ? __expf(s0v - mnew) : 0.f;
            float p1 = v1 ? __expf(s1v - mnew) : 0.f;
            float rs = grp16_sum(p0 + p1);
            l_r[r] = l_r[r] * al + rs;
            m_r[r] = mnew;
            #pragma unroll
            for (int nt = 0; nt < 8; ++nt) acc[nt][r] *= al;
            plds[w][ql][l16]      = bf16_of(p0);
            plds[w][ql][16 + l16] = bf16_of(p1);
        }
        short8 pa = *(const short8*)(&plds[w][l16][g4 * 8]);
        #pragma unroll
        for (int nt = 0; nt < 8; ++nt) {
            short8 vf = *(const short8*)(vT + ((size_t)kv * 128 + nt * 16 + l16) * 2048 + s0 + g4 * 8);
            acc[nt] = __builtin_amdgcn_mfma_f32_16x16x32_bf16(pa, vf, acc[nt], 0, 0, 0);
        }
    }
    #pragma unroll
    for (int r = 0; r < 4; ++r) {
        const int tq = t0 + g4 * 4 + r;
        const float rl = 1.0f / l_r[r];
        const float gc = gsig[tq * 24 + kv * 12 + w * 3 + 0];
        const float gs = gsig[tq * 24 + kv * 12 + w * 3 + 1];
        const float gw = gsig[tq * 24 + kv * 12 + w * 3 + 2];
        #pragma unroll
        for (int nt = 0; nt < 8; ++nt) {
            const size_t idx = (size_t)tq * 1024 + (kv * 4 + w) * 128 + nt * 16 + l16;
            out[idx] = gc * o_cmp[idx] + gs * (acc[nt][r] * rl) + gw * out[idx];
        }
    }
}

extern "C" void kernel_launch(void* const* d_in, const int* in_sizes, int n_in,
                              void* d_out, int out_size, void* d_ws, size_t ws_size,
                              hipStream_t stream)
{
    const float* x       = (const float*)d_in[0];
    const float* Wq      = (const float*)d_in[1];
    const float* Wk      = (const float*)d_in[2];
    const float* Wv      = (const float*)d_in[3];
    const float* Wg      = (const float*)d_in[4];
    const float* wk_pool = (const float*)d_in[5];
    const float* wv_pool = (const float*)d_in[6];
    const float* pe      = (const float*)d_in[7];
    float* out = (float*)d_out;
    float* ws  = (float*)d_ws;

    // ---- workspace layout (floats); total ~27.9 MB ----
    float* q     = ws;                         // 2,097,152
    float* k_raw = q + 2097152;                //   524,288
    float* v     = k_raw + 524288;             //   524,288
    float* gsig  = v + 524288;                 //    49,152
    float* k_cmp = gsig + 49152;               //    16,384
    float* v_cmp = k_cmp + 16384;              //    16,384
    unsigned long long* sel = (unsigned long long*)(v_cmp + 16384); // 8,192 f
    float* o_cmp = (float*)sel + 8192;         // 2,097,152
    // xhi/xlo alias o_cmp (dead before cmp_sel writes o_cmp)
    short* xhi   = (short*)o_cmp;              // 2,097,152 shorts
    short* xlo   = xhi + 2097152;              // 2,097,152 shorts
    short* qb    = (short*)(o_cmp + 2097152);  // 2,097,152 shorts
    short* krb   = qb + 2097152;               //   524,288 shorts
    short* vT    = krb + 524288;               //   524,288 shorts
    // wthi/wtlo alias qb..(vT+pad) (dead before rope_conv/vtrans write)
    short* wthi  = qb;                         // 1,638,400 shorts
    short* wtlo  = wthi + 1638400;             // 1,638,400 shorts (pad past vT)

    hipLaunchKernelGGL(xconv_kernel, dim3(2048), dim3(256), 0, stream, x, xhi, xlo);
    hipLaunchKernelGGL(wconv_kernel, dim3(50, 32), dim3(256), 0, stream,
                       Wq, Wk, Wv, Wg, wthi, wtlo);
    hipLaunchKernelGGL(proj_mfma_kernel, dim3(25, 16), dim3(512), 0, stream,
                       xhi, xlo, wthi, wtlo, q, k_raw, v, gsig);
    hipLaunchKernelGGL(rope_conv_kernel, dim3(512, 10), dim3(256), 0, stream,
                       q, k_raw, qb, krb);
    hipLaunchKernelGGL(vtrans_kernel, dim3(64, 4, 2), dim3(256), 0, stream,
                       v, vT);
    hipLaunchKernelGGL(pool_kernel, dim3(64), dim3(256), 0, stream,
                       k_raw, v, wk_pool, wv_pool, pe, k_cmp, v_cmp);
    hipLaunchKernelGGL(cmp_sel_kernel, dim3(2048, 2), dim3(64), 0, stream,
                       q, k_cmp, v_cmp, o_cmp, sel);
    hipLaunchKernelGGL(swa_kernel, dim3(64, 2), dim3(256), 0, stream,
                       qb, krb, vT, out);
    hipLaunchKernelGGL(slc_kernel, dim3(128, 2), dim3(256), 0, stream,
                       qb, krb, vT, sel, gsig, o_cmp, out);
}

// Round 5
// 238.355 us; speedup vs baseline: 3.5069x; 1.1257x over previous
//
#include <hip/hip_runtime.h>
#include <math.h>

#define NEGF  (-1e30f)
#define BIGF  (1000000.0f)
#define SCALE_ (0.08838834764831845f)   // 1/sqrt(128)
#define L2INV_ (0.20762050593046014f)   // log2(10000)/64

typedef __attribute__((ext_vector_type(4))) float f32x4;
typedef __attribute__((ext_vector_type(8))) short short8;
typedef __attribute__((ext_vector_type(4))) short short4v;
typedef __attribute__((ext_vector_type(8))) _Float16 half8;

#define GLDS16(gp, lp) __builtin_amdgcn_global_load_lds( \
    (const __attribute__((address_space(1))) void*)(gp), \
    (__attribute__((address_space(3))) void*)(lp), 16, 0, 0)

__device__ __forceinline__ float wave_max(float v) {
    #pragma unroll
    for (int off = 32; off >= 1; off >>= 1) v = fmaxf(v, __shfl_xor(v, off, 64));
    return v;
}
__device__ __forceinline__ float wave_sum(float v) {
    #pragma unroll
    for (int off = 32; off >= 1; off >>= 1) v += __shfl_xor(v, off, 64);
    return v;
}
__device__ __forceinline__ float grp16_max(float v) {
    #pragma unroll
    for (int off = 8; off >= 1; off >>= 1) v = fmaxf(v, __shfl_xor(v, off, 64));
    return v;
}
__device__ __forceinline__ float grp16_sum(float v) {
    #pragma unroll
    for (int off = 8; off >= 1; off >>= 1) v += __shfl_xor(v, off, 64);
    return v;
}
__device__ __forceinline__ short bf16_of(float f) {
    union { float f; unsigned u; } x; x.f = f;
    unsigned r = x.u + 0x7fffu + ((x.u >> 16) & 1u);
    return (short)(r >> 16);
}
__device__ __forceinline__ short f16_of(float f) {
    _Float16 h = (_Float16)f;
    union { _Float16 h; short s; } u; u.h = h;
    return u.s;
}
__device__ __forceinline__ float f32_of_f16(short s) {
    union { _Float16 h; short s; } u; u.s = s;
    return (float)u.h;
}

// -------- Kernel 0a: x (fp32) -> xhi/xlo fp16 split ------------------------
__global__ __launch_bounds__(256) void xconv_kernel(
    const float* __restrict__ x, short* __restrict__ xhi, short* __restrict__ xlo)
{
    const int i = blockIdx.x * 1024 + threadIdx.x * 4;
    float4 f = *(const float4*)(x + i);
    short4v hi, lo;
    float fv[4] = {f.x, f.y, f.z, f.w};
    #pragma unroll
    for (int c = 0; c < 4; ++c) {
        short h = f16_of(fv[c]);
        hi[c] = h;
        lo[c] = f16_of(fv[c] - f32_of_f16(h));
    }
    *(short4v*)(xhi + i) = hi;
    *(short4v*)(xlo + i) = lo;
}

// -------- Kernel 0b: W's -> WT fp16 split, transposed [1600][1024] ---------
__global__ __launch_bounds__(256) void wconv_kernel(
    const float* __restrict__ Wq, const float* __restrict__ Wk,
    const float* __restrict__ Wv, const float* __restrict__ Wg,
    short* __restrict__ wthi, short* __restrict__ wtlo)
{
    __shared__ float tile[32][33];
    const int ct = blockIdx.x, kt = blockIdx.y;
    const int c = threadIdx.x & 31, r0 = threadIdx.x >> 5;
    #pragma unroll
    for (int rr = 0; rr < 32; rr += 8) {
        int k = kt * 32 + r0 + rr;
        int gc = ct * 32 + c;
        float val;
        if (gc < 1024)      val = Wq[k * 1024 + gc];
        else if (gc < 1280) val = Wk[k * 256 + gc - 1024];
        else if (gc < 1536) val = Wv[k * 256 + gc - 1280];
        else if (gc < 1560) val = Wg[k * 24 + gc - 1536];
        else                val = 0.f;
        tile[r0 + rr][c] = val;
    }
    __syncthreads();
    #pragma unroll
    for (int rr = 0; rr < 32; rr += 8) {
        int col = ct * 32 + r0 + rr;
        int k = kt * 32 + c;
        float val = tile[c][r0 + rr];
        short hi = f16_of(val);
        short lo = f16_of(val - f32_of_f16(hi));
        wthi[(size_t)col * 1024 + k] = hi;
        wtlo[(size_t)col * 1024 + k] = lo;
    }
}

// -------- Kernel 1: projections via split-fp16 MFMA, LDS-staged ------------
__global__ __launch_bounds__(512) void proj_mfma_kernel(
    const short* __restrict__ xhi, const short* __restrict__ xlo,
    const short* __restrict__ wthi, const short* __restrict__ wtlo,
    float* __restrict__ q, float* __restrict__ k_raw,
    float* __restrict__ v, float* __restrict__ gsig)
{
    __shared__ __align__(16) short lds[24576];
    const int cb = blockIdx.x;
    const int tb = blockIdx.y;
    const int w = threadIdx.x >> 6;
    const int l = threadIdx.x & 63;
    const int l16 = l & 15, g4 = l >> 4;
    const int wm = w >> 1, wn = w & 1;
    const int row0 = tb * 128, col0 = cb * 64;

    const short* pAhi[2]; const short* pAlo[2];
    #pragma unroll
    for (int j = 0; j < 2; ++j) {
        int b = (2 * w + j) * 1024 + l * 16;
        int row = b >> 7;
        int kb = (b & 127) ^ ((row & 7) << 4);
        pAhi[j] = xhi + (size_t)(row0 + row) * 1024 + (kb >> 1);
        pAlo[j] = xlo + (size_t)(row0 + row) * 1024 + (kb >> 1);
    }
    const short* pBhi; const short* pBlo;
    {
        int b = w * 1024 + l * 16;
        int col = b >> 7;
        int kb = (b & 127) ^ ((col & 7) << 4);
        pBhi = wthi + (size_t)(col0 + col) * 1024 + (kb >> 1);
        pBlo = wtlo + (size_t)(col0 + col) * 1024 + (kb >> 1);
    }

    f32x4 acc[2][2];
    #pragma unroll
    for (int mt = 0; mt < 2; ++mt)
        #pragma unroll
        for (int nt = 0; nt < 2; ++nt) acc[mt][nt] = (f32x4)0.f;

    for (int k0 = 0; k0 < 1024; k0 += 64) {
        GLDS16(pAhi[0] + k0, &lds[(2 * w + 0) * 512]);
        GLDS16(pAhi[1] + k0, &lds[(2 * w + 1) * 512]);
        GLDS16(pAlo[0] + k0, &lds[8192 + (2 * w + 0) * 512]);
        GLDS16(pAlo[1] + k0, &lds[8192 + (2 * w + 1) * 512]);
        GLDS16(pBhi + k0,    &lds[16384 + w * 512]);
        GLDS16(pBlo + k0,    &lds[20480 + w * 512]);
        __syncthreads();
        #pragma unroll
        for (int ksub = 0; ksub < 2; ++ksub) {
            half8 ah[2], al[2], bh[2], bl[2];
            #pragma unroll
            for (int mt = 0; mt < 2; ++mt) {
                int row = wm * 32 + mt * 16 + l16;
                int kb = (ksub * 64 + g4 * 16) ^ ((row & 7) << 4);
                ah[mt] = *(const half8*)(const void*)&lds[row * 64 + (kb >> 1)];
                al[mt] = *(const half8*)(const void*)&lds[8192 + row * 64 + (kb >> 1)];
            }
            #pragma unroll
            for (int nt = 0; nt < 2; ++nt) {
                int col = wn * 32 + nt * 16 + l16;
                int kb = (ksub * 64 + g4 * 16) ^ ((col & 7) << 4);
                bh[nt] = *(const half8*)(const void*)&lds[16384 + col * 64 + (kb >> 1)];
                bl[nt] = *(const half8*)(const void*)&lds[20480 + col * 64 + (kb >> 1)];
            }
            #pragma unroll
            for (int mt = 0; mt < 2; ++mt)
                #pragma unroll
                for (int nt = 0; nt < 2; ++nt) {
                    acc[mt][nt] = __builtin_amdgcn_mfma_f32_16x16x32_f16(ah[mt], bh[nt], acc[mt][nt], 0, 0, 0);
                    acc[mt][nt] = __builtin_amdgcn_mfma_f32_16x16x32_f16(ah[mt], bl[nt], acc[mt][nt], 0, 0, 0);
                    acc[mt][nt] = __builtin_amdgcn_mfma_f32_16x16x32_f16(al[mt], bh[nt], acc[mt][nt], 0, 0, 0);
                }
        }
        __syncthreads();
    }
    #pragma unroll
    for (int mt = 0; mt < 2; ++mt) {
        #pragma unroll
        for (int r = 0; r < 4; ++r) {
            const int tt = row0 + wm * 32 + mt * 16 + g4 * 4 + r;
            #pragma unroll
            for (int nt = 0; nt < 2; ++nt) {
                const int cg = col0 + wn * 32 + nt * 16 + l16;
                const float val = acc[mt][nt][r];
                if (cg < 1024)      q[(size_t)tt * 1024 + cg] = val;
                else if (cg < 1280) k_raw[(size_t)tt * 256 + cg - 1024] = val;
                else if (cg < 1536) v[(size_t)tt * 256 + cg - 1280] = val;
                else if (cg < 1560) gsig[(size_t)tt * 24 + cg - 1536] = 1.0f / (1.0f + expf(-val));
            }
        }
    }
}

// ------ Kernel 2: RoPE on q (in place) and k, plus bf16 copies -------------
__global__ __launch_bounds__(256) void rope_conv_kernel(
    float* __restrict__ q, const float* __restrict__ k_raw,
    short* __restrict__ qb, short* __restrict__ krb)
{
    const int t = blockIdx.x * 4 + (threadIdx.x >> 6);
    const int h = blockIdx.y;
    const int i = threadIdx.x & 63;
    float inv = exp2f(-(float)i * L2INV_);
    float ang = (float)t * inv;
    float sn, cs;
    sincosf(ang, &sn, &cs);
    if (h < 8) {
        float* p = q + t * 1024 + h * 128;
        float x1 = p[i], x2 = p[i + 64];
        float r1 = x1 * cs - x2 * sn;
        float r2 = x1 * sn + x2 * cs;
        p[i] = r1; p[i + 64] = r2;
        qb[t * 1024 + h * 128 + i]      = bf16_of(r1);
        qb[t * 1024 + h * 128 + i + 64] = bf16_of(r2);
    } else {
        const float* s = k_raw + t * 256 + (h - 8) * 128;
        float x1 = s[i], x2 = s[i + 64];
        krb[t * 256 + (h - 8) * 128 + i]      = bf16_of(x1 * cs - x2 * sn);
        krb[t * 256 + (h - 8) * 128 + i + 64] = bf16_of(x1 * sn + x2 * cs);
    }
}

// ------ Kernel 2b: v (fp32 [s][kv][d]) -> vT bf16 [kv][d][s] ---------------
__global__ __launch_bounds__(256) void vtrans_kernel(
    const float* __restrict__ v, short* __restrict__ vT)
{
    __shared__ short tile[32][33];
    const int s0 = blockIdx.x * 32, d0 = blockIdx.y * 32, kv = blockIdx.z;
    const int c = threadIdx.x & 31, r0 = threadIdx.x >> 5;
    #pragma unroll
    for (int rr = 0; rr < 32; rr += 8) {
        int r = r0 + rr;
        tile[r][c] = bf16_of(v[((size_t)(s0 + r) * 2 + kv) * 128 + d0 + c]);
    }
    __syncthreads();
    #pragma unroll
    for (int rr = 0; rr < 32; rr += 8) {
        int r = r0 + rr;
        vT[((size_t)kv * 128 + d0 + r) * 2048 + s0 + c] = tile[c][r];
    }
}

// ------- Kernel 3: pooled k_cmp (roped at j*32) and v_cmp ------------------
__global__ __launch_bounds__(256) void pool_kernel(
    const float* __restrict__ k_raw, const float* __restrict__ v_raw,
    const float* __restrict__ wk_pool, const float* __restrict__ wv_pool,
    const float* __restrict__ pe, float* __restrict__ k_cmp, float* __restrict__ v_cmp)
{
    const int j = blockIdx.x;
    const int tid = threadIdx.x;
    const int kv = tid >> 7, d = tid & 127;
    float ak = 0.f, av = 0.f;
    for (int s = 0; s < 32; ++s) {
        float pev = pe[(kv * 32 + s) * 128 + d];
        float kk = k_raw[((j * 32 + s) * 2 + kv) * 128 + d] + pev;
        float vv = v_raw[((j * 32 + s) * 2 + kv) * 128 + d] + pev;
        ak += kk * wk_pool[kv * 32 + s];
        av += vv * wv_pool[kv * 32 + s];
    }
    __shared__ float sk[256];
    sk[tid] = ak;
    __syncthreads();
    int i = d & 63;
    float inv = exp2f(-(float)i * L2INV_);
    float ang = (float)(j * 32) * inv;
    float sn, cs; sincosf(ang, &sn, &cs);
    float x1 = sk[kv * 128 + i], x2 = sk[kv * 128 + i + 64];
    float outv = (d < 64) ? (x1 * cs - x2 * sn) : (x1 * sn + x2 * cs);
    k_cmp[(j * 2 + kv) * 128 + d] = outv;
    v_cmp[(j * 2 + kv) * 128 + d] = av;
}

// ------- Kernel 4: compressed attention + pw + top-8 selection (fp32) ------
__global__ __launch_bounds__(64) void cmp_sel_kernel(
    const float* __restrict__ q, const float* __restrict__ k_cmp,
    const float* __restrict__ v_cmp, float* __restrict__ o_cmp,
    unsigned long long* __restrict__ sel_mask)
{
    const int t = blockIdx.x;
    const int kv = blockIdx.y;
    const int lane = threadIdx.x;
    __shared__ float qs[4][128];
    __shared__ float ps[64];
    for (int idx = lane; idx < 512; idx += 64)
        qs[idx >> 7][idx & 127] = q[t * 1024 + kv * 512 + idx];
    __syncthreads();
    const int j = lane;
    const float4* krow = (const float4*)&k_cmp[(j * 2 + kv) * 128];
    const bool vis = (t >= j * 32 + 31);
    const bool anyvis = (t >= 31);
    float pw = 0.f;
    for (int g = 0; g < 4; ++g) {
        const float4* qrow = (const float4*)qs[g];
        float s = 0.f;
        #pragma unroll 8
        for (int ii = 0; ii < 32; ++ii) {
            float4 kk = krow[ii], qq = qrow[ii];
            s += kk.x * qq.x + kk.y * qq.y + kk.z * qq.z + kk.w * qq.w;
        }
        s *= SCALE_;
        s = vis ? s : NEGF;
        float m = wave_max(s);
        float e = expf(s - m);
        float sum = wave_sum(e);
        float p = anyvis ? (e / sum) : 0.f;
        pw += p;
        ps[lane] = p;
        __syncthreads();
        float o0 = 0.f, o1 = 0.f;
        for (int jj = 0; jj < 64; ++jj) {
            float pp = ps[jj];
            o0 += pp * v_cmp[(jj * 2 + kv) * 128 + lane];
            o1 += pp * v_cmp[(jj * 2 + kv) * 128 + lane + 64];
        }
        o_cmp[t * 1024 + kv * 512 + g * 128 + lane]      = o0;
        o_cmp[t * 1024 + kv * 512 + g * 128 + lane + 64] = o1;
        __syncthreads();
    }
    const int cur = t >> 5;
    const int curm1 = cur > 0 ? cur - 1 : 0;
    const bool forced = (j == 0) || (j == cur) || (j == curm1);
    const bool allowed = (j * 32 <= t);
    float sc = allowed ? (pw + (forced ? BIGF : 0.f)) : -1.0f;
    unsigned long long selm = 0ull;
    for (int it = 0; it < 8; ++it) {
        float bv = sc; int bi = j;
        #pragma unroll
        for (int off = 32; off >= 1; off >>= 1) {
            float ov = __shfl_xor(bv, off, 64);
            int   oi = __shfl_xor(bi, off, 64);
            if (ov > bv || (ov == bv && oi < bi)) { bv = ov; bi = oi; }
        }
        if (bv > -0.5f) selm |= (1ull << bi);
        if (j == bi) sc = -3e38f;
    }
    if (lane == 0) sel_mask[t * 2 + kv] = selm;
}

// ------- Kernel 5: fused selected + sliding-window attention + combine -----
// block = (16-query tile, kv), 8 waves: w<4 -> slc (g=w), w>=4 -> swa (g=w-4).
__global__ __launch_bounds__(512) void slcswa_kernel(
    const short* __restrict__ qb, const short* __restrict__ krb,
    const short* __restrict__ vT, const unsigned long long* __restrict__ sel,
    const float* __restrict__ gsig, const float* __restrict__ o_cmp,
    float* __restrict__ out)
{
    const int t0 = blockIdx.x * 16;
    const int kv = blockIdx.y;
    const int w  = threadIdx.x >> 6;       // 0..7
    const int l  = threadIdx.x & 63;
    const int l16 = l & 15, g4 = l >> 4;
    const int g  = w & 3;
    __shared__ __align__(16) short plds[8][16][40];
    __shared__ float o_part[4][16][132];   // swa normalized output per g
    __shared__ unsigned long long qm[16];
    __shared__ unsigned char blist[64];
    __shared__ int nbs;
    if (threadIdx.x < 16) qm[threadIdx.x] = sel[(size_t)(t0 + threadIdx.x) * 2 + kv];
    __syncthreads();
    if (threadIdx.x == 0) {
        unsigned long long u = 0ull;
        #pragma unroll
        for (int i = 0; i < 16; ++i) u |= qm[i];
        int n = 0;
        while (u) { blist[n++] = (unsigned char)(__ffsll((long long)u) - 1); u &= u - 1; }
        nbs = n;
    }
    __syncthreads();

    short8 qf[4];
    #pragma unroll
    for (int ks = 0; ks < 4; ++ks)
        qf[ks] = *(const short8*)(qb + ((size_t)(t0 + l16) * 8 + kv * 4 + g) * 128 + ks * 32 + g4 * 8);

    f32x4 acc[8];
    #pragma unroll
    for (int nt = 0; nt < 8; ++nt) acc[nt] = (f32x4)0.f;
    float m_r[4], l_r[4];
    #pragma unroll
    for (int r = 0; r < 4; ++r) { m_r[r] = NEGF; l_r[r] = 0.f; }

    if (w < 4) {
        // ---------------- selected branch ----------------
        const int nb = nbs;
        for (int bi = 0; bi < nb; ++bi) {
            const int j = blist[bi];
            const int s0 = j * 32;
            f32x4 sc[2];
            sc[0] = (f32x4)0.f; sc[1] = (f32x4)0.f;
            #pragma unroll
            for (int nt = 0; nt < 2; ++nt) {
                short8 kf[4];
                #pragma unroll
                for (int ks = 0; ks < 4; ++ks)
                    kf[ks] = *(const short8*)(krb + ((size_t)(s0 + nt * 16 + l16) * 2 + kv) * 128 + ks * 32 + g4 * 8);
                #pragma unroll
                for (int ks = 0; ks < 4; ++ks)
                    sc[nt] = __builtin_amdgcn_mfma_f32_16x16x32_bf16(qf[ks], kf[ks], sc[nt], 0, 0, 0);
            }
            #pragma unroll
            for (int r = 0; r < 4; ++r) {
                const int ql = g4 * 4 + r;
                const int tq = t0 + ql;
                const bool inmask = (qm[ql] >> j) & 1ull;
                const int sk0 = s0 + l16, sk1 = s0 + 16 + l16;
                const bool v0 = inmask && (sk0 <= tq);
                const bool v1 = inmask && (sk1 <= tq);
                float s0v = v0 ? sc[0][r] * SCALE_ : NEGF;
                float s1v = v1 ? sc[1][r] * SCALE_ : NEGF;
                float mx = grp16_max(fmaxf(s0v, s1v));
                float mnew = fmaxf(m_r[r], mx);
                float al = __expf(m_r[r] - mnew);
                float p0 = v0 ? __expf(s0v - mnew) : 0.f;
                float p1 = v1 ? __expf(s1v - mnew) : 0.f;
                float rs = grp16_sum(p0 + p1);
                l_r[r] = l_r[r] * al + rs;
                m_r[r] = mnew;
                #pragma unroll
                for (int nt = 0; nt < 8; ++nt) acc[nt][r] *= al;
                plds[w][ql][l16]      = bf16_of(p0);
                plds[w][ql][16 + l16] = bf16_of(p1);
            }
            short8 pa = *(const short8*)(&plds[w][l16][g4 * 8]);
            #pragma unroll
            for (int nt = 0; nt < 8; ++nt) {
                short8 vf = *(const short8*)(vT + ((size_t)kv * 128 + nt * 16 + l16) * 2048 + s0 + g4 * 8);
                acc[nt] = __builtin_amdgcn_mfma_f32_16x16x32_bf16(pa, vf, acc[nt], 0, 0, 0);
            }
        }
    } else {
        // ---------------- sliding-window branch ----------------
        const int sLo = (t0 >= 256) ? (t0 - 256) : 0;
        for (int s0 = sLo; s0 <= t0 + 15; s0 += 32) {
            f32x4 sc[2];
            sc[0] = (f32x4)0.f; sc[1] = (f32x4)0.f;
            #pragma unroll
            for (int nt = 0; nt < 2; ++nt) {
                short8 kf[4];
                int sr = s0 + nt * 16 + l16;
                if (sr > 2047) sr = 2047;           // clamp: finite garbage, masked below
                #pragma unroll
                for (int ks = 0; ks < 4; ++ks)
                    kf[ks] = *(const short8*)(krb + ((size_t)sr * 2 + kv) * 128 + ks * 32 + g4 * 8);
                #pragma unroll
                for (int ks = 0; ks < 4; ++ks)
                    sc[nt] = __builtin_amdgcn_mfma_f32_16x16x32_bf16(qf[ks], kf[ks], sc[nt], 0, 0, 0);
            }
            #pragma unroll
            for (int r = 0; r < 4; ++r) {
                const int tq = t0 + g4 * 4 + r;
                const int sk0 = s0 + l16, sk1 = s0 + 16 + l16;
                const bool v0 = (sk0 <= tq) && (sk0 >= tq - 256);
                const bool v1 = (sk1 <= tq) && (sk1 >= tq - 256);
                float s0v = v0 ? sc[0][r] * SCALE_ : NEGF;
                float s1v = v1 ? sc[1][r] * SCALE_ : NEGF;
                float mx = grp16_max(fmaxf(s0v, s1v));
                float mnew = fmaxf(m_r[r], mx);
                float al = __expf(m_r[r] - mnew);
                float p0 = v0 ? __expf(s0v - mnew) : 0.f;
                float p1 = v1 ? __expf(s1v - mnew) : 0.f;
                float rs = grp16_sum(p0 + p1);
                l_r[r] = l_r[r] * al + rs;
                m_r[r] = mnew;
                #pragma unroll
                for (int nt = 0; nt < 8; ++nt) acc[nt][r] *= al;
                plds[w][g4 * 4 + r][l16]      = bf16_of(p0);
                plds[w][g4 * 4 + r][16 + l16] = bf16_of(p1);
            }
            short8 pa = *(const short8*)(&plds[w][l16][g4 * 8]);
            int sc0 = s0 + g4 * 8;
            if (sc0 > 2040) sc0 = 2040;             // clamp vT column base
            #pragma unroll
            for (int nt = 0; nt < 8; ++nt) {
                short8 vf = *(const short8*)(vT + ((size_t)kv * 128 + nt * 16 + l16) * 2048 + sc0);
                acc[nt] = __builtin_amdgcn_mfma_f32_16x16x32_bf16(pa, vf, acc[nt], 0, 0, 0);
            }
        }
        // write normalized swa output to LDS
        #pragma unroll
        for (int r = 0; r < 4; ++r) {
            const float rl = 1.0f / l_r[r];
            #pragma unroll
            for (int nt = 0; nt < 8; ++nt)
                o_part[g][g4 * 4 + r][nt * 16 + l16] = acc[nt][r] * rl;
        }
    }
    __syncthreads();
    if (w < 4) {
        // ---------------- gated combine ----------------
        #pragma unroll
        for (int r = 0; r < 4; ++r) {
            const int tq = t0 + g4 * 4 + r;
            const float rl = 1.0f / l_r[r];
            const float gc = gsig[tq * 24 + kv * 12 + g * 3 + 0];
            const float gs = gsig[tq * 24 + kv * 12 + g * 3 + 1];
            const float gw = gsig[tq * 24 + kv * 12 + g * 3 + 2];
            #pragma unroll
            for (int nt = 0; nt < 8; ++nt) {
                const size_t idx = (size_t)tq * 1024 + (kv * 4 + g) * 128 + nt * 16 + l16;
                out[idx] = gc * o_cmp[idx] + gs * (acc[nt][r] * rl)
                         + gw * o_part[g][g4 * 4 + r][nt * 16 + l16];
            }
        }
    }
}

extern "C" void kernel_launch(void* const* d_in, const int* in_sizes, int n_in,
                              void* d_out, int out_size, void* d_ws, size_t ws_size,
                              hipStream_t stream)
{
    const float* x       = (const float*)d_in[0];
    const float* Wq      = (const float*)d_in[1];
    const float* Wk      = (const float*)d_in[2];
    const float* Wv      = (const float*)d_in[3];
    const float* Wg      = (const float*)d_in[4];
    const float* wk_pool = (const float*)d_in[5];
    const float* wv_pool = (const float*)d_in[6];
    const float* pe      = (const float*)d_in[7];
    float* out = (float*)d_out;
    float* ws  = (float*)d_ws;

    float* q     = ws;                         // 2,097,152
    float* k_raw = q + 2097152;                //   524,288
    float* v     = k_raw + 524288;             //   524,288
    float* gsig  = v + 524288;                 //    49,152
    float* k_cmp = gsig + 49152;               //    16,384
    float* v_cmp = k_cmp + 16384;              //    16,384
    unsigned long long* sel = (unsigned long long*)(v_cmp + 16384); // 8,192 f
    float* o_cmp = (float*)sel + 8192;         // 2,097,152
    short* xhi   = (short*)o_cmp;              // aliases o_cmp (dead before cmp_sel)
    short* xlo   = xhi + 2097152;
    short* qb    = (short*)(o_cmp + 2097152);  // 2,097,152 shorts
    short* krb   = qb + 2097152;               //   524,288 shorts
    short* vT    = krb + 524288;               //   524,288 shorts
    short* wthi  = qb;                         // aliases qb (dead before rope_conv)
    short* wtlo  = wthi + 1638400;

    hipLaunchKernelGGL(xconv_kernel, dim3(2048), dim3(256), 0, stream, x, xhi, xlo);
    hipLaunchKernelGGL(wconv_kernel, dim3(50, 32), dim3(256), 0, stream,
                       Wq, Wk, Wv, Wg, wthi, wtlo);
    hipLaunchKernelGGL(proj_mfma_kernel, dim3(25, 16), dim3(512), 0, stream,
                       xhi, xlo, wthi, wtlo, q, k_raw, v, gsig);
    hipLaunchKernelGGL(rope_conv_kernel, dim3(512, 10), dim3(256), 0, stream,
                       q, k_raw, qb, krb);
    hipLaunchKernelGGL(vtrans_kernel, dim3(64, 4, 2), dim3(256), 0, stream,
                       v, vT);
    hipLaunchKernelGGL(pool_kernel, dim3(64), dim3(256), 0, stream,
                       k_raw, v, wk_pool, wv_pool, pe, k_cmp, v_cmp);
    hipLaunchKernelGGL(cmp_sel_kernel, dim3(2048, 2), dim3(64), 0, stream,
                       q, k_cmp, v_cmp, o_cmp, sel);
    hipLaunchKernelGGL(slcswa_kernel, dim3(128, 2), dim3(512), 0, stream,
                       qb, krb, vT, sel, gsig, o_cmp, out);
}

// Round 6
// 238.239 us; speedup vs baseline: 3.5086x; 1.0005x over previous
//
#include <hip/hip_runtime.h>
#include <math.h>

#define NEGF  (-1e30f)
#define BIGF  (1000000.0f)
#define SCALE_ (0.08838834764831845f)   // 1/sqrt(128)
#define L2INV_ (0.20762050593046014f)   // log2(10000)/64

typedef __attribute__((ext_vector_type(4))) float f32x4;
typedef __attribute__((ext_vector_type(8))) short short8;
typedef __attribute__((ext_vector_type(4))) short short4v;
typedef __attribute__((ext_vector_type(8))) _Float16 half8;

#define GLDS16(gp, lp) __builtin_amdgcn_global_load_lds( \
    (const __attribute__((address_space(1))) void*)(gp), \
    (__attribute__((address_space(3))) void*)(lp), 16, 0, 0)

__device__ __forceinline__ float wave_max(float v) {
    #pragma unroll
    for (int off = 32; off >= 1; off >>= 1) v = fmaxf(v, __shfl_xor(v, off, 64));
    return v;
}
__device__ __forceinline__ float wave_sum(float v) {
    #pragma unroll
    for (int off = 32; off >= 1; off >>= 1) v += __shfl_xor(v, off, 64);
    return v;
}
__device__ __forceinline__ short bf16_of(float f) {
    union { float f; unsigned u; } x; x.f = f;
    unsigned r = x.u + 0x7fffu + ((x.u >> 16) & 1u);
    return (short)(r >> 16);
}
__device__ __forceinline__ short f16_of(float f) {
    _Float16 h = (_Float16)f;
    union { _Float16 h; short s; } u; u.h = h;
    return u.s;
}
__device__ __forceinline__ float f32_of_f16(short s) {
    union { _Float16 h; short s; } u; u.s = s;
    return (float)u.h;
}

// -------- Kernel 0a: x (fp32) -> xhi/xlo fp16 split ------------------------
__global__ __launch_bounds__(256) void xconv_kernel(
    const float* __restrict__ x, short* __restrict__ xhi, short* __restrict__ xlo)
{
    const int i = blockIdx.x * 1024 + threadIdx.x * 4;
    float4 f = *(const float4*)(x + i);
    short4v hi, lo;
    float fv[4] = {f.x, f.y, f.z, f.w};
    #pragma unroll
    for (int c = 0; c < 4; ++c) {
        short h = f16_of(fv[c]);
        hi[c] = h;
        lo[c] = f16_of(fv[c] - f32_of_f16(h));
    }
    *(short4v*)(xhi + i) = hi;
    *(short4v*)(xlo + i) = lo;
}

// -------- Kernel 0b: W's -> WT fp16 split, transposed [1600][1024] ---------
__global__ __launch_bounds__(256) void wconv_kernel(
    const float* __restrict__ Wq, const float* __restrict__ Wk,
    const float* __restrict__ Wv, const float* __restrict__ Wg,
    short* __restrict__ wthi, short* __restrict__ wtlo)
{
    __shared__ float tile[32][33];
    const int ct = blockIdx.x, kt = blockIdx.y;
    const int c = threadIdx.x & 31, r0 = threadIdx.x >> 5;
    #pragma unroll
    for (int rr = 0; rr < 32; rr += 8) {
        int k = kt * 32 + r0 + rr;
        int gc = ct * 32 + c;
        float val;
        if (gc < 1024)      val = Wq[k * 1024 + gc];
        else if (gc < 1280) val = Wk[k * 256 + gc - 1024];
        else if (gc < 1536) val = Wv[k * 256 + gc - 1280];
        else if (gc < 1560) val = Wg[k * 24 + gc - 1536];
        else                val = 0.f;
        tile[r0 + rr][c] = val;
    }
    __syncthreads();
    #pragma unroll
    for (int rr = 0; rr < 32; rr += 8) {
        int col = ct * 32 + r0 + rr;
        int k = kt * 32 + c;
        float val = tile[c][r0 + rr];
        short hi = f16_of(val);
        short lo = f16_of(val - f32_of_f16(hi));
        wthi[(size_t)col * 1024 + k] = hi;
        wtlo[(size_t)col * 1024 + k] = lo;
    }
}

// -------- Kernel 1: projections via split-fp16 MFMA, LDS-staged ------------
__global__ __launch_bounds__(512) void proj_mfma_kernel(
    const short* __restrict__ xhi, const short* __restrict__ xlo,
    const short* __restrict__ wthi, const short* __restrict__ wtlo,
    float* __restrict__ q, float* __restrict__ k_raw,
    float* __restrict__ v, float* __restrict__ gsig)
{
    __shared__ __align__(16) short lds[24576];
    const int cb = blockIdx.x;
    const int tb = blockIdx.y;
    const int w = threadIdx.x >> 6;
    const int l = threadIdx.x & 63;
    const int l16 = l & 15, g4 = l >> 4;
    const int wm = w >> 1, wn = w & 1;
    const int row0 = tb * 128, col0 = cb * 64;

    const short* pAhi[2]; const short* pAlo[2];
    #pragma unroll
    for (int j = 0; j < 2; ++j) {
        int b = (2 * w + j) * 1024 + l * 16;
        int row = b >> 7;
        int kb = (b & 127) ^ ((row & 7) << 4);
        pAhi[j] = xhi + (size_t)(row0 + row) * 1024 + (kb >> 1);
        pAlo[j] = xlo + (size_t)(row0 + row) * 1024 + (kb >> 1);
    }
    const short* pBhi; const short* pBlo;
    {
        int b = w * 1024 + l * 16;
        int col = b >> 7;
        int kb = (b & 127) ^ ((col & 7) << 4);
        pBhi = wthi + (size_t)(col0 + col) * 1024 + (kb >> 1);
        pBlo = wtlo + (size_t)(col0 + col) * 1024 + (kb >> 1);
    }

    f32x4 acc[2][2];
    #pragma unroll
    for (int mt = 0; mt < 2; ++mt)
        #pragma unroll
        for (int nt = 0; nt < 2; ++nt) acc[mt][nt] = (f32x4)0.f;

    for (int k0 = 0; k0 < 1024; k0 += 64) {
        GLDS16(pAhi[0] + k0, &lds[(2 * w + 0) * 512]);
        GLDS16(pAhi[1] + k0, &lds[(2 * w + 1) * 512]);
        GLDS16(pAlo[0] + k0, &lds[8192 + (2 * w + 0) * 512]);
        GLDS16(pAlo[1] + k0, &lds[8192 + (2 * w + 1) * 512]);
        GLDS16(pBhi + k0,    &lds[16384 + w * 512]);
        GLDS16(pBlo + k0,    &lds[20480 + w * 512]);
        __syncthreads();
        #pragma unroll
        for (int ksub = 0; ksub < 2; ++ksub) {
            half8 ah[2], al[2], bh[2], bl[2];
            #pragma unroll
            for (int mt = 0; mt < 2; ++mt) {
                int row = wm * 32 + mt * 16 + l16;
                int kb = (ksub * 64 + g4 * 16) ^ ((row & 7) << 4);
                ah[mt] = *(const half8*)(const void*)&lds[row * 64 + (kb >> 1)];
                al[mt] = *(const half8*)(const void*)&lds[8192 + row * 64 + (kb >> 1)];
            }
            #pragma unroll
            for (int nt = 0; nt < 2; ++nt) {
                int col = wn * 32 + nt * 16 + l16;
                int kb = (ksub * 64 + g4 * 16) ^ ((col & 7) << 4);
                bh[nt] = *(const half8*)(const void*)&lds[16384 + col * 64 + (kb >> 1)];
                bl[nt] = *(const half8*)(const void*)&lds[20480 + col * 64 + (kb >> 1)];
            }
            #pragma unroll
            for (int mt = 0; mt < 2; ++mt)
                #pragma unroll
                for (int nt = 0; nt < 2; ++nt) {
                    acc[mt][nt] = __builtin_amdgcn_mfma_f32_16x16x32_f16(ah[mt], bh[nt], acc[mt][nt], 0, 0, 0);
                    acc[mt][nt] = __builtin_amdgcn_mfma_f32_16x16x32_f16(ah[mt], bl[nt], acc[mt][nt], 0, 0, 0);
                    acc[mt][nt] = __builtin_amdgcn_mfma_f32_16x16x32_f16(al[mt], bh[nt], acc[mt][nt], 0, 0, 0);
                }
        }
        __syncthreads();
    }
    #pragma unroll
    for (int mt = 0; mt < 2; ++mt) {
        #pragma unroll
        for (int r = 0; r < 4; ++r) {
            const int tt = row0 + wm * 32 + mt * 16 + g4 * 4 + r;
            #pragma unroll
            for (int nt = 0; nt < 2; ++nt) {
                const int cg = col0 + wn * 32 + nt * 16 + l16;
                const float val = acc[mt][nt][r];
                if (cg < 1024)      q[(size_t)tt * 1024 + cg] = val;
                else if (cg < 1280) k_raw[(size_t)tt * 256 + cg - 1024] = val;
                else if (cg < 1536) v[(size_t)tt * 256 + cg - 1280] = val;
                else if (cg < 1560) gsig[(size_t)tt * 24 + cg - 1536] = 1.0f / (1.0f + expf(-val));
            }
        }
    }
}

// ------ Kernel 2: RoPE on q (in place) and k, plus bf16 copies -------------
__global__ __launch_bounds__(256) void rope_conv_kernel(
    float* __restrict__ q, const float* __restrict__ k_raw,
    short* __restrict__ qb, short* __restrict__ krb)
{
    const int t = blockIdx.x * 4 + (threadIdx.x >> 6);
    const int h = blockIdx.y;
    const int i = threadIdx.x & 63;
    float inv = exp2f(-(float)i * L2INV_);
    float ang = (float)t * inv;
    float sn, cs;
    sincosf(ang, &sn, &cs);
    if (h < 8) {
        float* p = q + t * 1024 + h * 128;
        float x1 = p[i], x2 = p[i + 64];
        float r1 = x1 * cs - x2 * sn;
        float r2 = x1 * sn + x2 * cs;
        p[i] = r1; p[i + 64] = r2;
        qb[t * 1024 + h * 128 + i]      = bf16_of(r1);
        qb[t * 1024 + h * 128 + i + 64] = bf16_of(r2);
    } else {
        const float* s = k_raw + t * 256 + (h - 8) * 128;
        float x1 = s[i], x2 = s[i + 64];
        krb[t * 256 + (h - 8) * 128 + i]      = bf16_of(x1 * cs - x2 * sn);
        krb[t * 256 + (h - 8) * 128 + i + 64] = bf16_of(x1 * sn + x2 * cs);
    }
}

// ------ Kernel 2b: v (fp32 [s][kv][d]) -> vT bf16 [kv][d][s] ---------------
__global__ __launch_bounds__(256) void vtrans_kernel(
    const float* __restrict__ v, short* __restrict__ vT)
{
    __shared__ short tile[32][33];
    const int s0 = blockIdx.x * 32, d0 = blockIdx.y * 32, kv = blockIdx.z;
    const int c = threadIdx.x & 31, r0 = threadIdx.x >> 5;
    #pragma unroll
    for (int rr = 0; rr < 32; rr += 8) {
        int r = r0 + rr;
        tile[r][c] = bf16_of(v[((size_t)(s0 + r) * 2 + kv) * 128 + d0 + c]);
    }
    __syncthreads();
    #pragma unroll
    for (int rr = 0; rr < 32; rr += 8) {
        int r = r0 + rr;
        vT[((size_t)kv * 128 + d0 + r) * 2048 + s0 + c] = tile[c][r];
    }
}

// ------- Kernel 3: pooled k_cmp (roped at j*32) and v_cmp ------------------
__global__ __launch_bounds__(256) void pool_kernel(
    const float* __restrict__ k_raw, const float* __restrict__ v_raw,
    const float* __restrict__ wk_pool, const float* __restrict__ wv_pool,
    const float* __restrict__ pe, float* __restrict__ k_cmp, float* __restrict__ v_cmp)
{
    const int j = blockIdx.x;
    const int tid = threadIdx.x;
    const int kv = tid >> 7, d = tid & 127;
    float ak = 0.f, av = 0.f;
    for (int s = 0; s < 32; ++s) {
        float pev = pe[(kv * 32 + s) * 128 + d];
        float kk = k_raw[((j * 32 + s) * 2 + kv) * 128 + d] + pev;
        float vv = v_raw[((j * 32 + s) * 2 + kv) * 128 + d] + pev;
        ak += kk * wk_pool[kv * 32 + s];
        av += vv * wv_pool[kv * 32 + s];
    }
    __shared__ float sk[256];
    sk[tid] = ak;
    __syncthreads();
    int i = d & 63;
    float inv = exp2f(-(float)i * L2INV_);
    float ang = (float)(j * 32) * inv;
    float sn, cs; sincosf(ang, &sn, &cs);
    float x1 = sk[kv * 128 + i], x2 = sk[kv * 128 + i + 64];
    float outv = (d < 64) ? (x1 * cs - x2 * sn) : (x1 * sn + x2 * cs);
    k_cmp[(j * 2 + kv) * 128 + d] = outv;
    v_cmp[(j * 2 + kv) * 128 + d] = av;
}

// ------- Kernel 4: compressed attention + pw + top-8 selection (fp32) ------
__global__ __launch_bounds__(64) void cmp_sel_kernel(
    const float* __restrict__ q, const float* __restrict__ k_cmp,
    const float* __restrict__ v_cmp, float* __restrict__ o_cmp,
    unsigned long long* __restrict__ sel_mask)
{
    const int t = blockIdx.x;
    const int kv = blockIdx.y;
    const int lane = threadIdx.x;
    __shared__ float qs[4][128];
    __shared__ float ps[64];
    for (int idx = lane; idx < 512; idx += 64)
        qs[idx >> 7][idx & 127] = q[t * 1024 + kv * 512 + idx];
    __syncthreads();
    const int j = lane;
    const float4* krow = (const float4*)&k_cmp[(j * 2 + kv) * 128];
    const bool vis = (t >= j * 32 + 31);
    const bool anyvis = (t >= 31);
    float pw = 0.f;
    for (int g = 0; g < 4; ++g) {
        const float4* qrow = (const float4*)qs[g];
        float s = 0.f;
        #pragma unroll 8
        for (int ii = 0; ii < 32; ++ii) {
            float4 kk = krow[ii], qq = qrow[ii];
            s += kk.x * qq.x + kk.y * qq.y + kk.z * qq.z + kk.w * qq.w;
        }
        s *= SCALE_;
        s = vis ? s : NEGF;
        float m = wave_max(s);
        float e = expf(s - m);
        float sum = wave_sum(e);
        float p = anyvis ? (e / sum) : 0.f;
        pw += p;
        ps[lane] = p;
        __syncthreads();
        float o0 = 0.f, o1 = 0.f;
        for (int jj = 0; jj < 64; ++jj) {
            float pp = ps[jj];
            o0 += pp * v_cmp[(jj * 2 + kv) * 128 + lane];
            o1 += pp * v_cmp[(jj * 2 + kv) * 128 + lane + 64];
        }
        o_cmp[t * 1024 + kv * 512 + g * 128 + lane]      = o0;
        o_cmp[t * 1024 + kv * 512 + g * 128 + lane + 64] = o1;
        __syncthreads();
    }
    const int cur = t >> 5;
    const int curm1 = cur > 0 ? cur - 1 : 0;
    const bool forced = (j == 0) || (j == cur) || (j == curm1);
    const bool allowed = (j * 32 <= t);
    float sc = allowed ? (pw + (forced ? BIGF : 0.f)) : -1.0f;
    unsigned long long selm = 0ull;
    for (int it = 0; it < 8; ++it) {
        float bv = sc; int bi = j;
        #pragma unroll
        for (int off = 32; off >= 1; off >>= 1) {
            float ov = __shfl_xor(bv, off, 64);
            int   oi = __shfl_xor(bi, off, 64);
            if (ov > bv || (ov == bv && oi < bi)) { bv = ov; bi = oi; }
        }
        if (bv > -0.5f) selm |= (1ull << bi);
        if (j == bi) sc = -3e38f;
    }
    if (lane == 0) sel_mask[t * 2 + kv] = selm;
}

// ------- Kernel 5: fused slc+swa, swapped-operand QK^T (per-lane softmax) --
// block = (16-query tile, kv), 8 waves: w<4 -> slc (g=w), w>=4 -> swa (g=w-4).
__global__ __launch_bounds__(512) void slcswa_kernel(
    const short* __restrict__ qb, const short* __restrict__ krb,
    const short* __restrict__ vT, const unsigned long long* __restrict__ sel,
    const float* __restrict__ gsig, const float* __restrict__ o_cmp,
    float* __restrict__ out)
{
    const int t0 = blockIdx.x * 16;
    const int kv = blockIdx.y;
    const int w  = threadIdx.x >> 6;       // 0..7
    const int l  = threadIdx.x & 63;
    const int l16 = l & 15, g4 = l >> 4;
    const int g  = w & 3;
    __shared__ __align__(16) short plds[8][16][40];
    __shared__ float o_slc[4][16][132];
    __shared__ float o_swa[4][16][132];
    __shared__ float gl[16][12];
    __shared__ unsigned long long qm[16];
    __shared__ unsigned char blist[64];
    __shared__ int nbs;
    if (threadIdx.x < 16) qm[threadIdx.x] = sel[(size_t)(t0 + threadIdx.x) * 2 + kv];
    if (threadIdx.x >= 64 && threadIdx.x < 256) {
        int idx = threadIdx.x - 64;
        gl[idx / 12][idx % 12] = gsig[(size_t)(t0 + idx / 12) * 24 + kv * 12 + idx % 12];
    }
    __syncthreads();
    if (threadIdx.x == 0) {
        unsigned long long u = 0ull;
        #pragma unroll
        for (int i = 0; i < 16; ++i) u |= qm[i];
        int n = 0;
        while (u) { blist[n++] = (unsigned char)(__ffsll((long long)u) - 1); u &= u - 1; }
        nbs = n;
    }
    __syncthreads();

    // Q fragment: lane (l16,g4) holds q[t0+l16][ks*32+g4*8 ..+8] -> B-frag (cols=queries)
    short8 qf[4];
    #pragma unroll
    for (int ks = 0; ks < 4; ++ks)
        qf[ks] = *(const short8*)(qb + ((size_t)(t0 + l16) * 8 + kv * 4 + g) * 128 + ks * 32 + g4 * 8);

    f32x4 acc[8];                          // O^T: acc[dt][r] = O[d=dt*16+g4*4+r][query l16]
    #pragma unroll
    for (int dt = 0; dt < 8; ++dt) acc[dt] = (f32x4)0.f;
    float m_r = NEGF, l_r = 0.f;           // per-lane (query l16)
    const int tq = t0 + l16;

    if (w < 4) {
        // ---------------- selected branch ----------------
        const unsigned long long myqm = qm[l16];
        const int nb = nbs;
        for (int bi = 0; bi < nb; ++bi) {
            const int j = blist[bi];
            const int s0 = j * 32;
            f32x4 sct[2];
            sct[0] = (f32x4)0.f; sct[1] = (f32x4)0.f;
            #pragma unroll
            for (int nt = 0; nt < 2; ++nt) {
                short8 kf[4];
                #pragma unroll
                for (int ks = 0; ks < 4; ++ks)
                    kf[ks] = *(const short8*)(krb + ((size_t)(s0 + nt * 16 + l16) * 2 + kv) * 128 + ks * 32 + g4 * 8);
                #pragma unroll
                for (int ks = 0; ks < 4; ++ks)
                    sct[nt] = __builtin_amdgcn_mfma_f32_16x16x32_bf16(kf[ks], qf[ks], sct[nt], 0, 0, 0);
            }
            const bool inm = (myqm >> j) & 1ull;
            float p[8];
            float mx = NEGF;
            #pragma unroll
            for (int nt = 0; nt < 2; ++nt)
                #pragma unroll
                for (int r = 0; r < 4; ++r) {
                    const int key = s0 + nt * 16 + g4 * 4 + r;
                    const bool vv = inm && (key <= tq);
                    const float sv = vv ? sct[nt][r] * SCALE_ : NEGF;
                    p[nt * 4 + r] = sv;
                    mx = fmaxf(mx, sv);
                }
            mx = fmaxf(mx, __shfl_xor(mx, 16, 64));
            mx = fmaxf(mx, __shfl_xor(mx, 32, 64));
            const float mnew = fmaxf(m_r, mx);
            const float al = __expf(m_r - mnew);
            float rs = 0.f;
            #pragma unroll
            for (int i = 0; i < 8; ++i) { float pv = __expf(p[i] - mnew); p[i] = pv; rs += pv; }
            rs += __shfl_xor(rs, 16, 64);
            rs += __shfl_xor(rs, 32, 64);
            l_r = l_r * al + rs;
            m_r = mnew;
            #pragma unroll
            for (int dt = 0; dt < 8; ++dt) acc[dt] *= al;
            #pragma unroll
            for (int nt = 0; nt < 2; ++nt)
                #pragma unroll
                for (int r = 0; r < 4; ++r)
                    plds[w][l16][nt * 16 + g4 * 4 + r] = bf16_of(p[nt * 4 + r]);
            short8 pa = *(const short8*)(&plds[w][l16][g4 * 8]);
            #pragma unroll
            for (int dt = 0; dt < 8; ++dt) {
                short8 vf = *(const short8*)(vT + ((size_t)kv * 128 + dt * 16 + l16) * 2048 + s0 + g4 * 8);
                acc[dt] = __builtin_amdgcn_mfma_f32_16x16x32_bf16(vf, pa, acc[dt], 0, 0, 0);
            }
        }
        const float rl = 1.0f / l_r;
        #pragma unroll
        for (int dt = 0; dt < 8; ++dt)
            #pragma unroll
            for (int r = 0; r < 4; ++r)
                o_slc[g][l16][dt * 16 + g4 * 4 + r] = acc[dt][r] * rl;
    } else {
        // ---------------- sliding-window branch ----------------
        const int sLo = (t0 >= 256) ? (t0 - 256) : 0;
        for (int s0 = sLo; s0 <= t0 + 15; s0 += 32) {
            f32x4 sct[2];
            sct[0] = (f32x4)0.f; sct[1] = (f32x4)0.f;
            #pragma unroll
            for (int nt = 0; nt < 2; ++nt) {
                short8 kf[4];
                int sr = s0 + nt * 16 + l16;
                if (sr > 2047) sr = 2047;          // clamp; masked below
                #pragma unroll
                for (int ks = 0; ks < 4; ++ks)
                    kf[ks] = *(const short8*)(krb + ((size_t)sr * 2 + kv) * 128 + ks * 32 + g4 * 8);
                #pragma unroll
                for (int ks = 0; ks < 4; ++ks)
                    sct[nt] = __builtin_amdgcn_mfma_f32_16x16x32_bf16(kf[ks], qf[ks], sct[nt], 0, 0, 0);
            }
            float p[8];
            float mx = NEGF;
            #pragma unroll
            for (int nt = 0; nt < 2; ++nt)
                #pragma unroll
                for (int r = 0; r < 4; ++r) {
                    const int key = s0 + nt * 16 + g4 * 4 + r;
                    const bool vv = (key <= tq) && (key >= tq - 256);
                    const float sv = vv ? sct[nt][r] * SCALE_ : NEGF;
                    p[nt * 4 + r] = sv;
                    mx = fmaxf(mx, sv);
                }
            mx = fmaxf(mx, __shfl_xor(mx, 16, 64));
            mx = fmaxf(mx, __shfl_xor(mx, 32, 64));
            const float mnew = fmaxf(m_r, mx);
            const float al = __expf(m_r - mnew);
            float rs = 0.f;
            #pragma unroll
            for (int i = 0; i < 8; ++i) { float pv = __expf(p[i] - mnew); p[i] = pv; rs += pv; }
            rs += __shfl_xor(rs, 16, 64);
            rs += __shfl_xor(rs, 32, 64);
            l_r = l_r * al + rs;
            m_r = mnew;
            #pragma unroll
            for (int dt = 0; dt < 8; ++dt) acc[dt] *= al;
            #pragma unroll
            for (int nt = 0; nt < 2; ++nt)
                #pragma unroll
                for (int r = 0; r < 4; ++r)
                    plds[w][l16][nt * 16 + g4 * 4 + r] = bf16_of(p[nt * 4 + r]);
            short8 pa = *(const short8*)(&plds[w][l16][g4 * 8]);
            int sc0 = s0 + g4 * 8;
            if (sc0 > 2040) sc0 = 2040;            // clamp; those p's are 0
            #pragma unroll
            for (int dt = 0; dt < 8; ++dt) {
                short8 vf = *(const short8*)(vT + ((size_t)kv * 128 + dt * 16 + l16) * 2048 + sc0);
                acc[dt] = __builtin_amdgcn_mfma_f32_16x16x32_bf16(vf, pa, acc[dt], 0, 0, 0);
            }
        }
        const float rl = 1.0f / l_r;
        #pragma unroll
        for (int dt = 0; dt < 8; ++dt)
            #pragma unroll
            for (int r = 0; r < 4; ++r)
                o_swa[g][l16][dt * 16 + g4 * 4 + r] = acc[dt][r] * rl;
    }
    __syncthreads();
    // ---------------- gated combine (coalesced, all 512 threads) -----------
    for (int idx = threadIdx.x; idx < 8192; idx += 512) {
        const int qq = idx >> 9, c = idx & 511;
        const int gg = c >> 7, d = c & 127;
        const size_t oidx = (size_t)(t0 + qq) * 1024 + kv * 512 + c;
        out[oidx] = gl[qq][gg * 3 + 0] * o_cmp[oidx]
                  + gl[qq][gg * 3 + 1] * o_slc[gg][qq][d]
                  + gl[qq][gg * 3 + 2] * o_swa[gg][qq][d];
    }
}

extern "C" void kernel_launch(void* const* d_in, const int* in_sizes, int n_in,
                              void* d_out, int out_size, void* d_ws, size_t ws_size,
                              hipStream_t stream)
{
    const float* x       = (const float*)d_in[0];
    const float* Wq      = (const float*)d_in[1];
    const float* Wk      = (const float*)d_in[2];
    const float* Wv      = (const float*)d_in[3];
    const float* Wg      = (const float*)d_in[4];
    const float* wk_pool = (const float*)d_in[5];
    const float* wv_pool = (const float*)d_in[6];
    const float* pe      = (const float*)d_in[7];
    float* out = (float*)d_out;
    float* ws  = (float*)d_ws;

    float* q     = ws;                         // 2,097,152
    float* k_raw = q + 2097152;                //   524,288
    float* v     = k_raw + 524288;             //   524,288
    float* gsig  = v + 524288;                 //    49,152
    float* k_cmp = gsig + 49152;               //    16,384
    float* v_cmp = k_cmp + 16384;              //    16,384
    unsigned long long* sel = (unsigned long long*)(v_cmp + 16384); // 8,192 f
    float* o_cmp = (float*)sel + 8192;         // 2,097,152
    short* xhi   = (short*)o_cmp;              // aliases o_cmp (dead before cmp_sel)
    short* xlo   = xhi + 2097152;
    short* qb    = (short*)(o_cmp + 2097152);  // 2,097,152 shorts
    short* krb   = qb + 2097152;               //   524,288 shorts
    short* vT    = krb + 524288;               //   524,288 shorts
    short* wthi  = qb;                         // aliases qb (dead before rope_conv)
    short* wtlo  = wthi + 1638400;

    hipLaunchKernelGGL(xconv_kernel, dim3(2048), dim3(256), 0, stream, x, xhi, xlo);
    hipLaunchKernelGGL(wconv_kernel, dim3(50, 32), dim3(256), 0, stream,
                       Wq, Wk, Wv, Wg, wthi, wtlo);
    hipLaunchKernelGGL(proj_mfma_kernel, dim3(25, 16), dim3(512), 0, stream,
                       xhi, xlo, wthi, wtlo, q, k_raw, v, gsig);
    hipLaunchKernelGGL(rope_conv_kernel, dim3(512, 10), dim3(256), 0, stream,
                       q, k_raw, qb, krb);
    hipLaunchKernelGGL(vtrans_kernel, dim3(64, 4, 2), dim3(256), 0, stream,
                       v, vT);
    hipLaunchKernelGGL(pool_kernel, dim3(64), dim3(256), 0, stream,
                       k_raw, v, wk_pool, wv_pool, pe, k_cmp, v_cmp);
    hipLaunchKernelGGL(cmp_sel_kernel, dim3(2048, 2), dim3(64), 0, stream,
                       q, k_cmp, v_cmp, o_cmp, sel);
    hipLaunchKernelGGL(slcswa_kernel, dim3(128, 2), dim3(512), 0, stream,
                       qb, krb, vT, sel, gsig, o_cmp, out);
}